// Round 14
// baseline (209.628 us; speedup 1.0000x reference)
//
#include <hip/hip_runtime.h>
#include <math.h>

#define DI 384   // d_inner

typedef __attribute__((ext_vector_type(8))) short bf8v;   // 8 bf16
typedef __attribute__((ext_vector_type(4))) float f4v;    // 4 fp32

__device__ __forceinline__ f4v mfma16(bf8v a, bf8v b, f4v c) {
  return __builtin_amdgcn_mfma_f32_16x16x32_bf16(a, b, c, 0, 0, 0);
}

__device__ __forceinline__ int trf(int l) { return ((l & 63) << 6) | (l >> 6); }
__device__ __forceinline__ float gelu_f(float x) {
  return 0.5f * x * (1.0f + erff(x * 0.7071067811865475f));
}
__device__ __forceinline__ float softplus_f(float x) {
  return (x > 20.0f) ? x : log1pf(expf(x));
}
__device__ __forceinline__ unsigned short f2bf(float f) {
  unsigned u = __float_as_uint(f);
  unsigned r = (u + 0x7fff + ((u >> 16) & 1)) >> 16;
  return (unsigned short)r;
}
__device__ __forceinline__ float bf2f(unsigned short h) {
  return __uint_as_float(((unsigned)h) << 16);
}
__device__ __forceinline__ unsigned short el16(uint2 v, int i) {
  unsigned w = (i < 2) ? v.x : v.y;
  return (unsigned short)((i & 1) ? (w >> 16) : (w & 0xffffu));
}
__device__ __forceinline__ unsigned short el8(uint4 v, int i) {
  unsigned w = ((const unsigned*)&v)[i >> 1];
  return (unsigned short)((i & 1) ? (w >> 16) : (w & 0xffffu));
}
// fp32[8] -> bf16 hi/lo 8-vectors (used during GEMM staging; no separate cvt pass)
__device__ __forceinline__ void cvt8v(const float* __restrict__ p, bf8v& hv, bf8v& lv) {
#pragma unroll
  for (int i = 0; i < 8; ++i) {
    float v = p[i];
    unsigned short h = f2bf(v);
    hv[i] = (short)h;
    lv[i] = (short)f2bf(v - bf2f(h));
  }
}
// element offset in a [R][64] u16 plane, XOR-swizzled per 8-elem block
__device__ __forceinline__ int swz(int row, int col) {
  return (row << 6) + ((((col >> 3) ^ (row & 7)) << 3) | (col & 7));
}
__device__ __forceinline__ int foff(int row, int cb) {
  return (row << 6) + ((cb ^ (row & 7)) << 3);
}

// ---- in_proj (MFMA): x[8192,192] @ w[768,192]^T ; fp32 operands split at stage
__global__ __launch_bounds__(256) void k_inproj(const float* __restrict__ x,
                                                const float* __restrict__ wip,
                                                unsigned short* __restrict__ xr_hi,
                                                unsigned short* __restrict__ xr_lo,
                                                float* __restrict__ zg) {
  const int K = 192;
  __shared__ unsigned short Ah[4096], Al[4096], Bh[4096], Bl[4096];
  int tid = threadIdx.x;
  int lane = tid & 63, w = tid >> 6;
  int cl = lane & 15, kb = lane >> 4;
  int wm = w >> 1, wn = w & 1;
  int m0 = blockIdx.y * 64, n0 = blockIdx.x * 64;
  f4v acc[2][2];
  acc[0][0] = acc[0][1] = acc[1][0] = acc[1][1] = (f4v){0.f, 0.f, 0.f, 0.f};
  for (int k0 = 0; k0 < K; k0 += 64) {
#pragma unroll
    for (int u = 0; u < 2; ++u) {
      int unit = tid + u * 256;
      int row = unit >> 3, blk = unit & 7;
      int e = foff(row, blk);
      bf8v hv, lv;
      cvt8v(x + (size_t)(m0 + row) * K + k0 + blk * 8, hv, lv);
      *(bf8v*)(Ah + e) = hv;
      *(bf8v*)(Al + e) = lv;
      cvt8v(wip + (size_t)(n0 + row) * K + k0 + blk * 8, hv, lv);
      *(bf8v*)(Bh + e) = hv;
      *(bf8v*)(Bl + e) = lv;
    }
    __syncthreads();
#pragma unroll
    for (int chunk = 0; chunk < 2; ++chunk) {
      int cb = chunk * 4 + kb;
      bf8v ah[2], al[2], bh[2], bl[2];
#pragma unroll
      for (int mi = 0; mi < 2; ++mi) {
        ah[mi] = *(const bf8v*)(Ah + foff(wm * 32 + mi * 16 + cl, cb));
        al[mi] = *(const bf8v*)(Al + foff(wm * 32 + mi * 16 + cl, cb));
      }
#pragma unroll
      for (int ni = 0; ni < 2; ++ni) {
        bh[ni] = *(const bf8v*)(Bh + foff(wn * 32 + ni * 16 + cl, cb));
        bl[ni] = *(const bf8v*)(Bl + foff(wn * 32 + ni * 16 + cl, cb));
      }
#pragma unroll
      for (int mi = 0; mi < 2; ++mi)
#pragma unroll
        for (int ni = 0; ni < 2; ++ni) {
          acc[mi][ni] = mfma16(ah[mi], bh[ni], acc[mi][ni]);
          acc[mi][ni] = mfma16(ah[mi], bl[ni], acc[mi][ni]);
          acc[mi][ni] = mfma16(al[mi], bh[ni], acc[mi][ni]);
        }
    }
    __syncthreads();
  }
#pragma unroll
  for (int mi = 0; mi < 2; ++mi)
#pragma unroll
    for (int ni = 0; ni < 2; ++ni)
#pragma unroll
      for (int i = 0; i < 4; ++i) {
        int m = m0 + wm * 32 + mi * 16 + kb * 4 + i;
        int n = n0 + wn * 32 + ni * 16 + cl;
        float v = acc[mi][ni][i];
        if (n < DI) {
          unsigned short hh = f2bf(v);
          xr_hi[(size_t)m * DI + n] = hh;
          xr_lo[(size_t)m * DI + n] = f2bf(v - bf2f(hh));
        } else {
          zg[(size_t)m * DI + (n - DI)] = gelu_f(v);
        }
      }
}

// ---- depthwise 3x3 conv + bias + gelu -> xi planes; 8-channel vectorized
__global__ __launch_bounds__(256) void k_conv(const unsigned short* __restrict__ xrh,
                                              const unsigned short* __restrict__ xrl,
                                              const float* __restrict__ cw,
                                              const float* __restrict__ cb,
                                              unsigned short* __restrict__ xhi,
                                              unsigned short* __restrict__ xlo,
                                              unsigned short* __restrict__ xthi,
                                              unsigned short* __restrict__ xtlo) {
  int idx = blockIdx.x * 256 + threadIdx.x;  // over 2*4096*48
  int c8 = idx % 48;
  int c = c8 * 8;
  int lf = idx / 48;
  int b = lf >> 12;
  int l = lf & 4095;
  int h = l >> 6, w = l & 63;
  float acc[8];
#pragma unroll
  for (int i = 0; i < 8; ++i) acc[i] = cb[c + i];
#pragma unroll
  for (int dh = -1; dh <= 1; ++dh) {
    int hh = h + dh;
    if ((unsigned)hh >= 64u) continue;
#pragma unroll
    for (int dw = -1; dw <= 1; ++dw) {
      int ww = w + dw;
      if ((unsigned)ww >= 64u) continue;
      size_t o = ((size_t)((b << 12) | (hh << 6) | ww)) * DI + c;
      uint4 hv = *(const uint4*)(xrh + o);
      uint4 lv = *(const uint4*)(xrl + o);
      int jj = (dh + 1) * 3 + (dw + 1);
#pragma unroll
      for (int i = 0; i < 8; ++i)
        acc[i] += (bf2f(el8(hv, i)) + bf2f(el8(lv, i))) * cw[(c + i) * 9 + jj];
    }
  }
  unsigned ho[4], lo4[4];
#pragma unroll
  for (int ii = 0; ii < 4; ++ii) {
    float g0 = gelu_f(acc[2 * ii]);
    float g1 = gelu_f(acc[2 * ii + 1]);
    unsigned short h0 = f2bf(g0), h1 = f2bf(g1);
    unsigned short L0 = f2bf(g0 - bf2f(h0)), L1 = f2bf(g1 - bf2f(h1));
    ho[ii] = (unsigned)h0 | ((unsigned)h1 << 16);
    lo4[ii] = (unsigned)L0 | ((unsigned)L1 << 16);
  }
  size_t oo = (size_t)lf * DI + c;
  *(uint4*)(xhi + oo) = *(const uint4*)ho;
  *(uint4*)(xlo + oo) = *(const uint4*)lo4;
  size_t tof = ((size_t)((b << 12) | trf(l))) * DI + c;  // row-contiguous in c
  *(uint4*)(xthi + tof) = *(const uint4*)ho;
  *(uint4*)(xtlo + tof) = *(const uint4*)lo4;
}

// ---- x_proj (MFMA, direction-PAIRED): one A-tile serves dir z (rows m) and
//      dir z+2 (rows 4095-m). z=0: xi->dirs{0,2}, z=1: xit->dirs{1,3}.
__global__ __launch_bounds__(256) void k_xproj(const unsigned short* __restrict__ xhi,
                                               const unsigned short* __restrict__ xlo,
                                               const unsigned short* __restrict__ xthi,
                                               const unsigned short* __restrict__ xtlo,
                                               const float* __restrict__ wxp,
                                               const float* __restrict__ dt_bias,
                                               float* __restrict__ dt_buf,
                                               unsigned short* __restrict__ Bhi,
                                               unsigned short* __restrict__ Blo,
                                               unsigned short* __restrict__ Chi,
                                               unsigned short* __restrict__ Clo) {
  const int K = DI, N = 140;
  int z = blockIdx.z;  // plane/dir-pair select
  __shared__ unsigned short Ah[4096], Al[4096];
  __shared__ unsigned short B0h[4096], B0l[4096], B1h[4096], B1l[4096];
  int tid = threadIdx.x;
  int lane = tid & 63, w = tid >> 6;
  int cl = lane & 15, kb = lane >> 4;
  int wm = w >> 1, wn = w & 1;
  int m0 = blockIdx.y * 64, n0 = blockIdx.x * 64;
  const unsigned short* xph = z ? xthi : xhi;
  const unsigned short* xpl = z ? xtlo : xlo;
  const float* wk0 = wxp + (size_t)z * N * K;
  const float* wk1 = wxp + (size_t)(z + 2) * N * K;
  f4v acc[2][2][2];  // [dir][mi][ni]
#pragma unroll
  for (int d = 0; d < 2; ++d)
#pragma unroll
    for (int mi = 0; mi < 2; ++mi)
#pragma unroll
      for (int ni = 0; ni < 2; ++ni) acc[d][mi][ni] = (f4v){0.f, 0.f, 0.f, 0.f};
  for (int k0 = 0; k0 < K; k0 += 64) {
#pragma unroll
    for (int u = 0; u < 2; ++u) {
      int unit = tid + u * 256;
      int row = unit >> 3, blk = unit & 7;
      int e = foff(row, blk);
      size_t ga = (size_t)(m0 + row) * DI + k0 + blk * 8;
      *(bf8v*)(Ah + e) = *(const bf8v*)(xph + ga);
      *(bf8v*)(Al + e) = *(const bf8v*)(xpl + ga);
      int n = n0 + row;
      if (n < N) {
        bf8v hv, lv;
        cvt8v(wk0 + (size_t)n * K + k0 + blk * 8, hv, lv);
        *(bf8v*)(B0h + e) = hv;
        *(bf8v*)(B0l + e) = lv;
        cvt8v(wk1 + (size_t)n * K + k0 + blk * 8, hv, lv);
        *(bf8v*)(B1h + e) = hv;
        *(bf8v*)(B1l + e) = lv;
      } else {
        bf8v zv = {0, 0, 0, 0, 0, 0, 0, 0};
        *(bf8v*)(B0h + e) = zv;
        *(bf8v*)(B0l + e) = zv;
        *(bf8v*)(B1h + e) = zv;
        *(bf8v*)(B1l + e) = zv;
      }
    }
    __syncthreads();
#pragma unroll
    for (int chunk = 0; chunk < 2; ++chunk) {
      int cb = chunk * 4 + kb;
      bf8v ah[2], al[2];
#pragma unroll
      for (int mi = 0; mi < 2; ++mi) {
        ah[mi] = *(const bf8v*)(Ah + foff(wm * 32 + mi * 16 + cl, cb));
        al[mi] = *(const bf8v*)(Al + foff(wm * 32 + mi * 16 + cl, cb));
      }
#pragma unroll
      for (int ni = 0; ni < 2; ++ni) {
        int brow = wn * 32 + ni * 16 + cl;
        bf8v b0h = *(const bf8v*)(B0h + foff(brow, cb));
        bf8v b0l = *(const bf8v*)(B0l + foff(brow, cb));
        bf8v b1h = *(const bf8v*)(B1h + foff(brow, cb));
        bf8v b1l = *(const bf8v*)(B1l + foff(brow, cb));
#pragma unroll
        for (int mi = 0; mi < 2; ++mi) {
          acc[0][mi][ni] = mfma16(ah[mi], b0h, acc[0][mi][ni]);
          acc[0][mi][ni] = mfma16(ah[mi], b0l, acc[0][mi][ni]);
          acc[0][mi][ni] = mfma16(al[mi], b0h, acc[0][mi][ni]);
          acc[1][mi][ni] = mfma16(ah[mi], b1h, acc[1][mi][ni]);
          acc[1][mi][ni] = mfma16(ah[mi], b1l, acc[1][mi][ni]);
          acc[1][mi][ni] = mfma16(al[mi], b1h, acc[1][mi][ni]);
        }
      }
    }
    __syncthreads();
  }
#pragma unroll
  for (int d = 0; d < 2; ++d) {
    int kd = z + d * 2;
#pragma unroll
    for (int mi = 0; mi < 2; ++mi)
#pragma unroll
      for (int ni = 0; ni < 2; ++ni)
#pragma unroll
        for (int i = 0; i < 4; ++i) {
          int m = m0 + wm * 32 + mi * 16 + kb * 4 + i;
          int n = n0 + wn * 32 + ni * 16 + cl;
          if (n >= N) continue;
          float v = acc[d][mi][ni][i];
          int b = m >> 12;
          int l = m & 4095;
          if (d) l = 4095 - l;
          if (n < 12) {
            dt_buf[(((size_t)(b * 48 + kd * 12 + n)) << 12) + l] =
                softplus_f(v + dt_bias[kd * 12 + n]);
          } else if (n < 76) {
            size_t off = (((size_t)((b * 4 + kd) << 12)) + l) * 64 + (n - 12);
            unsigned short hh = f2bf(v);
            Bhi[off] = hh;
            Blo[off] = f2bf(v - bf2f(hh));
          } else {
            size_t off = (((size_t)((b * 4 + kd) << 12)) + l) * 64 + (n - 76);
            unsigned short hh = f2bf(v);
            Chi[off] = hh;
            Clo[off] = f2bf(v - bf2f(hh));
          }
        }
  }
}

// ---- dt cumsum precompute: acum (inclusive, fp32) + chunk decay
__global__ __launch_bounds__(256) void k_dtacum(const float* __restrict__ dt_buf,
                                                const float* __restrict__ A_logs,
                                                float* __restrict__ ac_buf,
                                                float* __restrict__ cdec) {
  int bh = blockIdx.y;                           // 0..95
  int c = blockIdx.x * 4 + (threadIdx.x >> 6);   // 0..63
  int lane = threadIdx.x & 63;
  int h = bh % 48;
  size_t o = ((size_t)bh << 12) + c * 64 + lane;
  float dtv = dt_buf[o];
  float v = dtv * (-__expf(A_logs[h]));
#pragma unroll
  for (int off = 1; off < 64; off <<= 1) {
    float u = __shfl_up(v, off, 64);
    if (lane >= off) v += u;
  }
  ac_buf[o] = v;
  if (lane == 63) cdec[bh * 64 + c] = __expf(v);
}

// ---- D1 (MFMA, hi-only): single barrier per head via double-buffered xw
__global__ __launch_bounds__(256) void k_states(const unsigned short* __restrict__ xhi,
                                                const unsigned short* __restrict__ xthi,
                                                const float* __restrict__ dt_buf,
                                                const float* __restrict__ ac_buf,
                                                const unsigned short* __restrict__ Bhi,
                                                unsigned short* __restrict__ Shi) {
  int c = blockIdx.x, k = blockIdx.y >> 1, g = blockIdx.y & 1, b = blockIdx.z;
  __shared__ unsigned short Bt_h[4096];     // [n][q] transposed, swizzled
  __shared__ unsigned short xwb[2][2048];   // [p][q] swizzled, double-buffered
  int tid = threadIdx.x;
  int lane = tid & 63, w = tid >> 6;
  int cl = lane & 15, kb = lane >> 4;
  const unsigned short* xp = (k & 1) ? xthi : xhi;
  int pg = tid & 7, qq = tid >> 3;  // p=pg*4..+3, q0=qq*2
  int h0_ = k * 12 + g * 6;
  // prefetch head 0 x + dt + ac
  uint2 xgA[2], xgB[2];
#pragma unroll
  for (int qp = 0; qp < 2; ++qp) {
    int i = c * 64 + qq * 2 + qp;
    if (k & 2) i = 4095 - i;
    xgA[qp] = *(const uint2*)(xp + ((size_t)((b << 12) + i)) * DI + (g * 6) * 32 + pg * 4);
  }
  size_t dto0 = (((size_t)(b * 48 + h0_)) << 12) + c * 64 + lane;
  float dtA = dt_buf[dto0];
  float acA = ac_buf[dto0];
  float dtB, acB;
  // transpose-stage B -> Bt[n][q] (covered by first loop barrier)
  size_t Bbase = (((size_t)((b * 4 + k) << 12)) + c * 64) * 64;
  {
    int n = lane;
#pragma unroll
    for (int it = 0; it < 8; ++it) {
      int q0 = 2 * (w + it * 4);
      unsigned short h0 = Bhi[Bbase + (size_t)q0 * 64 + n];
      unsigned short h1 = Bhi[Bbase + (size_t)(q0 + 1) * 64 + n];
      *(unsigned int*)(Bt_h + swz(n, q0)) = (unsigned)h0 | ((unsigned)h1 << 16);
    }
  }
  for (int rr = 0; rr < 6; ++rr) {
    int r = g * 6 + rr;
    int h = k * 12 + r;
    float v = acA;
    float alast = __shfl(v, 63, 64);
    float wq = dtA * __expf(alast - v);
    float w0 = __shfl(wq, qq * 2, 64), w1 = __shfl(wq, qq * 2 + 1, 64);
    unsigned short* xw_h = xwb[rr & 1];
#pragma unroll
    for (int pi = 0; pi < 4; ++pi) {
      int p = pg * 4 + pi;
      unsigned short h0 = f2bf(bf2f(el16(xgA[0], pi)) * w0);
      unsigned short h1 = f2bf(bf2f(el16(xgA[1], pi)) * w1);
      *(unsigned int*)(xw_h + swz(p, qq * 2)) = (unsigned)h0 | ((unsigned)h1 << 16);
    }
    __syncthreads();  // xw[rr&1]+Bt ready; prev head's MFMA (other buffer) may lag safely
    // prefetch next head
    if (rr < 5) {
#pragma unroll
      for (int qp = 0; qp < 2; ++qp) {
        int i = c * 64 + qq * 2 + qp;
        if (k & 2) i = 4095 - i;
        xgB[qp] = *(const uint2*)(xp + ((size_t)((b << 12) + i)) * DI + (r + 1) * 32 + pg * 4);
      }
      size_t dton = (((size_t)(b * 48 + h + 1)) << 12) + c * 64 + lane;
      dtB = dt_buf[dton];
      acB = ac_buf[dton];
    }
    f4v acc0 = {0.f, 0.f, 0.f, 0.f}, acc1 = {0.f, 0.f, 0.f, 0.f};
#pragma unroll
    for (int chunk = 0; chunk < 2; ++chunk) {
      int cb_ = chunk * 4 + kb;
      bf8v bh = *(const bf8v*)(Bt_h + foff(w * 16 + cl, cb_));
      bf8v a0h = *(const bf8v*)(xw_h + foff(cl, cb_));
      bf8v a1h = *(const bf8v*)(xw_h + foff(16 + cl, cb_));
      acc0 = mfma16(a0h, bh, acc0);
      acc1 = mfma16(a1h, bh, acc1);
    }
    size_t sbase = ((size_t)(b * 48 + h) * 64 + c) * 2048;
#pragma unroll
    for (int i = 0; i < 4; ++i) {
      int prow = kb * 4 + i;
      int n = w * 16 + cl;
      Shi[sbase + (size_t)prow * 64 + n] = f2bf(acc0[i]);
      Shi[sbase + (size_t)(16 + prow) * 64 + n] = f2bf(acc1[i]);
    }
    xgA[0] = xgB[0];
    xgA[1] = xgB[1];
    dtA = dtB;
    acA = acB;
  }
}

// ---- D2: inter-chunk scan, in place bf16, 8-deep prefetched load pipeline
__global__ __launch_bounds__(256) void k_scan(unsigned short* __restrict__ Shi,
                                              const float* __restrict__ cdec) {
  int j = blockIdx.x;   // 0..7
  int bh = blockIdx.y;  // 0..95
  int tid = threadIdx.x;
  size_t base0 = (size_t)bh * 64 * 2048 + j * 256 + tid;
  float pre[8];
#pragma unroll
  for (int jj = 0; jj < 8; ++jj) pre[jj] = bf2f(Shi[base0 + (size_t)jj * 2048]);
  float S = 0.0f;
#pragma unroll 8
  for (int c = 0; c < 64; ++c) {
    float cd = cdec[bh * 64 + c];
    size_t idx = base0 + (size_t)c * 2048;
    float tmp = pre[c & 7];
    if (c + 8 < 64) pre[c & 7] = bf2f(Shi[idx + 8 * 2048]);
    Shi[idx] = f2bf(S);
    S = cd * S + tmp;
  }
}

// ---- D3 (MFMA): CB^T once (regs); per head (SINGLE barrier, double-buffered G/X):
//      Y = G_h @ x + exp(Ac)*(C @ prev^T) + D*x ; ys fp32 (bf16 stores regressed R12)
__global__ __launch_bounds__(256) void k_out(const unsigned short* __restrict__ xhi,
                                             const unsigned short* __restrict__ xlo,
                                             const unsigned short* __restrict__ xthi,
                                             const unsigned short* __restrict__ xtlo,
                                             const float* __restrict__ dt_buf,
                                             const float* __restrict__ ac_buf,
                                             const unsigned short* __restrict__ Bhi,
                                             const unsigned short* __restrict__ Blo,
                                             const unsigned short* __restrict__ Chi,
                                             const unsigned short* __restrict__ Clo,
                                             const float* __restrict__ Ds,
                                             const unsigned short* __restrict__ Phi,
                                             float* __restrict__ ys) {
  int c = blockIdx.x, k = blockIdx.y >> 1, g = blockIdx.y & 1, b = blockIdx.z;
  __shared__ unsigned short C_h[4096], C_l[4096];  // [q][n] swizzled
  __shared__ unsigned short Gb[2][4096];           // B hi/lo in CB phase, then G dbuf
  __shared__ unsigned short Xb[2][4096];           // X_h|X_l double-buffered
  int tid = threadIdx.x;
  int lane = tid & 63, w = tid >> 6;
  int cl = lane & 15, kb = lane >> 4;
  const unsigned short* xph = (k & 1) ? xthi : xhi;
  const unsigned short* xpl = (k & 1) ? xtlo : xlo;
  int pg = tid & 7, sq = tid >> 3;  // p=pg*4..+3, s0=sq*2
  int h0_ = k * 12 + g * 6;
  // prefetch head 0: X (wide), P frags, dt, acum
  uint2 xghA[2], xglA[2], xghB[2], xglB[2];
#pragma unroll
  for (int sp = 0; sp < 2; ++sp) {
    int i = c * 64 + sq * 2 + sp;
    if (k & 2) i = 4095 - i;
    size_t o = ((size_t)((b << 12) + i)) * DI + (g * 6) * 32 + pg * 4;
    xghA[sp] = *(const uint2*)(xph + o);
    xglA[sp] = *(const uint2*)(xpl + o);
  }
  bf8v pfA[2][2], pfB[2][2];
  {
    size_t pb = ((size_t)(b * 48 + h0_) * 64 + c) * 2048;
#pragma unroll
    for (int chunk = 0; chunk < 2; ++chunk) {
      int cb_ = chunk * 4 + kb;
      pfA[chunk][0] = *(const bf8v*)(Phi + pb + (size_t)cl * 64 + cb_ * 8);
      pfA[chunk][1] = *(const bf8v*)(Phi + pb + (size_t)(16 + cl) * 64 + cb_ * 8);
    }
  }
  size_t dto0 = (((size_t)(b * 48 + h0_)) << 12) + c * 64 + lane;
  float dtA = dt_buf[dto0];
  float vA = ac_buf[dto0];
  float dtB, vB;
  // stage C (C_h/C_l) + B (hi->Gb[0], lo->Gb[1]) for CB^T
  size_t base64 = (((size_t)((b * 4 + k) << 12)) + c * 64) * 64;
  {
    int n0 = (tid & 31) * 2;
    int qq = tid >> 5;
#pragma unroll
    for (int it = 0; it < 8; ++it) {
      int q = qq + it * 8;
      size_t off = base64 + (size_t)q * 64 + n0;
      int e = swz(q, n0);
      *(unsigned int*)(C_h + e) = *(const unsigned int*)(Chi + off);
      *(unsigned int*)(C_l + e) = *(const unsigned int*)(Clo + off);
      *(unsigned int*)(Gb[0] + e) = *(const unsigned int*)(Bhi + off);
      *(unsigned int*)(Gb[1] + e) = *(const unsigned int*)(Blo + off);
    }
  }
  __syncthreads();
  bf8v caf_h[2], caf_l[2];
#pragma unroll
  for (int chunk = 0; chunk < 2; ++chunk) {
    caf_h[chunk] = *(const bf8v*)(C_h + foff(w * 16 + cl, chunk * 4 + kb));
    caf_l[chunk] = *(const bf8v*)(C_l + foff(w * 16 + cl, chunk * 4 + kb));
  }
  f4v cbt[4];
#pragma unroll
  for (int St = 0; St < 4; ++St) cbt[St] = (f4v){0.f, 0.f, 0.f, 0.f};
#pragma unroll
  for (int St = 0; St < 4; ++St) {
    int srow = St * 16 + cl;
#pragma unroll
    for (int chunk = 0; chunk < 2; ++chunk) {
      bf8v bh = *(const bf8v*)(Gb[0] + foff(srow, chunk * 4 + kb));
      bf8v bl = *(const bf8v*)(Gb[1] + foff(srow, chunk * 4 + kb));
      cbt[St] = mfma16(caf_h[chunk], bh, cbt[St]);
      cbt[St] = mfma16(caf_h[chunk], bl, cbt[St]);
      cbt[St] = mfma16(caf_l[chunk], bh, cbt[St]);
    }
  }
  __syncthreads();  // all waves done reading B from Gb before head-0 overwrites
  for (int rr = 0; rr < 6; ++rr) {
    int r = g * 6 + rr;
    int h = k * 12 + r;
    float dtv = dtA;
    float v = vA;
    float ea = __expf(v);
    unsigned short* Gc = Gb[rr & 1];
    unsigned short* X_h = Xb[rr & 1];
    unsigned short* X_l = Xb[rr & 1] + 2048;
    // write prefetched X regs -> LDS (buffer rr&1; prev head's MFMA uses other buffer)
#pragma unroll
    for (int pi = 0; pi < 4; ++pi) {
      int p = pg * 4 + pi;
      int e = swz(p, sq * 2);
      *(unsigned int*)(X_h + e) =
          (unsigned)el16(xghA[0], pi) | ((unsigned)el16(xghA[1], pi) << 16);
      *(unsigned int*)(X_l + e) =
          (unsigned)el16(xglA[0], pi) | ((unsigned)el16(xglA[1], pi) << 16);
    }
    // build G[q][s] (hi only) from register CB; evq reused as epilogue exp(Ac[q])
    float vq[4], evq[4];
#pragma unroll
    for (int i = 0; i < 4; ++i) {
      vq[i] = __shfl(v, w * 16 + kb * 4 + i, 64);
      evq[i] = __shfl(ea, w * 16 + kb * 4 + i, 64);
    }
#pragma unroll
    for (int St = 0; St < 4; ++St) {
      int s = St * 16 + cl;
      float vs = __shfl(v, s, 64);
      float dts = __shfl(dtv, s, 64);
#pragma unroll
      for (int i = 0; i < 4; ++i) {
        int q = w * 16 + kb * 4 + i;
        float gv = (q >= s) ? cbt[St][i] * __expf(vq[i] - vs) * dts : 0.0f;
        Gc[swz(q, s)] = f2bf(gv);
      }
    }
    __syncthreads();  // single barrier: staging + G of THIS head ready
    // prefetch NEXT head's X + P + dt + acum (consumed next iteration)
    if (rr < 5) {
#pragma unroll
      for (int sp = 0; sp < 2; ++sp) {
        int i = c * 64 + sq * 2 + sp;
        if (k & 2) i = 4095 - i;
        size_t o = ((size_t)((b << 12) + i)) * DI + (r + 1) * 32 + pg * 4;
        xghB[sp] = *(const uint2*)(xph + o);
        xglB[sp] = *(const uint2*)(xpl + o);
      }
      size_t pbn = ((size_t)(b * 48 + h + 1) * 64 + c) * 2048;
#pragma unroll
      for (int chunk = 0; chunk < 2; ++chunk) {
        int cb_ = chunk * 4 + kb;
        pfB[chunk][0] = *(const bf8v*)(Phi + pbn + (size_t)cl * 64 + cb_ * 8);
        pfB[chunk][1] = *(const bf8v*)(Phi + pbn + (size_t)(16 + cl) * 64 + cb_ * 8);
      }
      size_t dton = (((size_t)(b * 48 + h + 1)) << 12) + c * 64 + lane;
      dtB = dt_buf[dton];
      vB = ac_buf[dton];
    }
    f4v aD0 = {0.f, 0.f, 0.f, 0.f}, aD1 = aD0, aO0 = aD0, aO1 = aD0;
#pragma unroll
    for (int chunk = 0; chunk < 2; ++chunk) {
      int cb_ = chunk * 4 + kb;
      int qrow = w * 16 + cl;
      bf8v gh = *(const bf8v*)(Gc + foff(qrow, cb_));
      bf8v x0h = *(const bf8v*)(X_h + foff(cl, cb_));
      bf8v x0l = *(const bf8v*)(X_l + foff(cl, cb_));
      bf8v x1h = *(const bf8v*)(X_h + foff(16 + cl, cb_));
      bf8v x1l = *(const bf8v*)(X_l + foff(16 + cl, cb_));
      aD0 = mfma16(gh, x0h, aD0);
      aD0 = mfma16(gh, x0l, aD0);
      aD1 = mfma16(gh, x1h, aD1);
      aD1 = mfma16(gh, x1l, aD1);
      aO0 = mfma16(caf_h[chunk], pfA[chunk][0], aO0);
      aO0 = mfma16(caf_l[chunk], pfA[chunk][0], aO0);
      aO1 = mfma16(caf_h[chunk], pfA[chunk][1], aO1);
      aO1 = mfma16(caf_l[chunk], pfA[chunk][1], aO1);
    }
    float D0 = Ds[h * 32 + cl], D1 = Ds[h * 32 + 16 + cl];
    size_t ybase = ((size_t)((b * 4 + k) << 12) + c * 64) * DI + r * 32;
#pragma unroll
    for (int i = 0; i < 4; ++i) {
      int q = w * 16 + kb * 4 + i;
      float eaq = evq[i];
      int e0 = swz(cl, q), e1 = swz(16 + cl, q);
      float xv0 = bf2f(X_h[e0]) + bf2f(X_l[e0]);
      float xv1 = bf2f(X_h[e1]) + bf2f(X_l[e1]);
      ys[ybase + (size_t)q * DI + cl] = aD0[i] + eaq * aO0[i] + D0 * xv0;
      ys[ybase + (size_t)q * DI + 16 + cl] = aD1[i] + eaq * aO1[i] + D1 * xv1;
    }
#pragma unroll
    for (int chunk = 0; chunk < 2; ++chunk) {
      pfA[chunk][0] = pfB[chunk][0];
      pfA[chunk][1] = pfB[chunk][1];
    }
    xghA[0] = xghB[0]; xghA[1] = xghB[1];
    xglA[0] = xglB[0]; xglA[1] = xglB[1];
    dtA = dtB;
    vA = vB;
  }
}

// ---- combine 4 directions + LayerNorm + gate -> y2 (bf16 hi only)
__global__ __launch_bounds__(128) void k_ln(const float* __restrict__ ys,
                                            const float* __restrict__ zg,
                                            const float* __restrict__ gg,
                                            const float* __restrict__ bb,
                                            unsigned short* __restrict__ y2h) {
  int row = blockIdx.x;
  int b = row >> 12, l = row & 4095;
  int l1 = trf(l);
  int l2 = 4095 - l;
  int l3 = 4095 - l1;
  int tid = threadIdx.x;
  float v[3];
  size_t base = ((size_t)(b * 4)) << 12;
#pragma unroll
  for (int j = 0; j < 3; ++j) {
    int d = tid + j * 128;
    v[j] = ys[(base + l) * DI + d] + ys[(base + 4096 + l1) * DI + d] +
           ys[(base + 8192 + l2) * DI + d] + ys[(base + 12288 + l3) * DI + d];
  }
  __shared__ float red[2];
  float s = v[0] + v[1] + v[2];
#pragma unroll
  for (int off = 32; off > 0; off >>= 1) s += __shfl_down(s, off, 64);
  if ((tid & 63) == 0) red[tid >> 6] = s;
  __syncthreads();
  float mu = (red[0] + red[1]) * (1.0f / 384.0f);
  __syncthreads();
  float d2 = 0.0f;
#pragma unroll
  for (int j = 0; j < 3; ++j) {
    float dd = v[j] - mu;
    d2 += dd * dd;
  }
#pragma unroll
  for (int off = 32; off > 0; off >>= 1) d2 += __shfl_down(d2, off, 64);
  if ((tid & 63) == 0) red[tid >> 6] = d2;
  __syncthreads();
  float rstd = rsqrtf((red[0] + red[1]) * (1.0f / 384.0f) + 1e-5f);
#pragma unroll
  for (int j = 0; j < 3; ++j) {
    int d = tid + j * 128;
    float yv = (v[j] - mu) * rstd * gg[d] + bb[d];
    float o = yv * zg[(size_t)row * DI + d];
    y2h[(size_t)row * DI + d] = f2bf(o);
  }
}

// ---- out_proj (MFMA): y2(bf16)[8192,384] @ w[192,384]^T -> out fp32 [8192,192]
__global__ __launch_bounds__(256) void k_outproj(const unsigned short* __restrict__ Ahi,
                                                 const float* __restrict__ wop,
                                                 float* __restrict__ out) {
  const int K = DI, NO = 192;
  __shared__ unsigned short Ah[4096], Bh[4096], Bl[4096];
  int tid = threadIdx.x;
  int lane = tid & 63, w = tid >> 6;
  int cl = lane & 15, kb = lane >> 4;
  int wm = w >> 1, wn = w & 1;
  int m0 = blockIdx.y * 64, n0 = blockIdx.x * 64;
  f4v acc[2][2];
  acc[0][0] = acc[0][1] = acc[1][0] = acc[1][1] = (f4v){0.f, 0.f, 0.f, 0.f};
  for (int k0 = 0; k0 < K; k0 += 64) {
#pragma unroll
    for (int u = 0; u < 2; ++u) {
      int unit = tid + u * 256;
      int row = unit >> 3, blk = unit & 7;
      int e = foff(row, blk);
      *(bf8v*)(Ah + e) = *(const bf8v*)(Ahi + (size_t)(m0 + row) * K + k0 + blk * 8);
      bf8v hv, lv;
      cvt8v(wop + (size_t)(n0 + row) * K + k0 + blk * 8, hv, lv);
      *(bf8v*)(Bh + e) = hv;
      *(bf8v*)(Bl + e) = lv;
    }
    __syncthreads();
#pragma unroll
    for (int chunk = 0; chunk < 2; ++chunk) {
      int cb = chunk * 4 + kb;
      bf8v ah[2], bh[2], bl[2];
#pragma unroll
      for (int mi = 0; mi < 2; ++mi)
        ah[mi] = *(const bf8v*)(Ah + foff(wm * 32 + mi * 16 + cl, cb));
#pragma unroll
      for (int ni = 0; ni < 2; ++ni) {
        bh[ni] = *(const bf8v*)(Bh + foff(wn * 32 + ni * 16 + cl, cb));
        bl[ni] = *(const bf8v*)(Bl + foff(wn * 32 + ni * 16 + cl, cb));
      }
#pragma unroll
      for (int mi = 0; mi < 2; ++mi)
#pragma unroll
        for (int ni = 0; ni < 2; ++ni) {
          acc[mi][ni] = mfma16(ah[mi], bh[ni], acc[mi][ni]);
          acc[mi][ni] = mfma16(ah[mi], bl[ni], acc[mi][ni]);
        }
    }
    __syncthreads();
  }
#pragma unroll
  for (int mi = 0; mi < 2; ++mi)
#pragma unroll
    for (int ni = 0; ni < 2; ++ni)
#pragma unroll
      for (int i = 0; i < 4; ++i) {
        int m = m0 + wm * 32 + mi * 16 + kb * 4 + i;
        int n = n0 + wn * 32 + ni * 16 + cl;
        out[(size_t)m * NO + n] = acc[mi][ni][i];
      }
}

extern "C" void kernel_launch(void* const* d_in, const int* in_sizes, int n_in,
                              void* d_out, int out_size, void* d_ws, size_t ws_size,
                              hipStream_t stream) {
  const float* x = (const float*)d_in[0];
  const float* in_proj_w = (const float*)d_in[1];
  const float* conv_w = (const float*)d_in[2];
  const float* conv_b = (const float*)d_in[3];
  const float* x_proj_w = (const float*)d_in[4];
  const float* A_logs = (const float*)d_in[5];
  const float* Ds = (const float*)d_in[6];
  const float* dt_bias = (const float*)d_in[7];
  const float* out_norm_g = (const float*)d_in[8];
  const float* out_norm_b = (const float*)d_in[9];
  const float* out_proj_w = (const float*)d_in[10];
  float* out = (float*)d_out;

  float* ws = (float*)d_ws;
  float* xi_raw = ws;                        // 3145728 f (xr hi/lo planes, later y2)
  float* zg = xi_raw + 3145728;              // 3145728 f
  float* dt_buf = zg + 3145728;              // 393216 f
  float* ac_buf = dt_buf + 393216;           // 393216 f
  float* cdec = ac_buf + 393216;             // 6144 f
  float* ys = cdec + 6144;                   // 12582912 f
  unsigned short* u16p = (unsigned short*)(ys + 12582912);
  unsigned short* Shi = u16p;    u16p += 12582912;   // states/prev (bf16, hi only)
  unsigned short* xi_hi = u16p;  u16p += 3145728;
  unsigned short* xi_lo = u16p;  u16p += 3145728;
  unsigned short* xit_hi = u16p; u16p += 3145728;    // transposed hi plane
  unsigned short* xit_lo = u16p; u16p += 3145728;    // transposed lo plane
  unsigned short* Bhi = u16p;    u16p += 2097152;
  unsigned short* Blo = u16p;    u16p += 2097152;
  unsigned short* Chi = u16p;    u16p += 2097152;
  unsigned short* Clo = u16p;    u16p += 2097152;
  unsigned short* xr_hi = (unsigned short*)xi_raw;  // in_proj out, dead after conv
  unsigned short* xr_lo = xr_hi + 3145728;
  unsigned short* y2h = xr_hi;                      // alias: xr dead after conv

  k_inproj<<<dim3(12, 128), 256, 0, stream>>>(x, in_proj_w, xr_hi, xr_lo, zg);
  k_conv<<<dim3(1536), 256, 0, stream>>>(xr_hi, xr_lo, conv_w, conv_b, xi_hi, xi_lo,
                                         xit_hi, xit_lo);
  k_xproj<<<dim3(3, 128, 2), 256, 0, stream>>>(xi_hi, xi_lo, xit_hi, xit_lo, x_proj_w,
                                               dt_bias, dt_buf, Bhi, Blo, Chi, Clo);
  k_dtacum<<<dim3(16, 96), 256, 0, stream>>>(dt_buf, A_logs, ac_buf, cdec);
  k_states<<<dim3(64, 8, 2), 256, 0, stream>>>(xi_hi, xit_hi, dt_buf, ac_buf, Bhi, Shi);
  k_scan<<<dim3(8, 96), 256, 0, stream>>>(Shi, cdec);
  k_out<<<dim3(64, 8, 2), 256, 0, stream>>>(xi_hi, xi_lo, xit_hi, xit_lo, dt_buf,
                                            ac_buf, Bhi, Blo, Chi, Clo, Ds, Shi, ys);
  k_ln<<<dim3(8192), 128, 0, stream>>>(ys, zg, out_norm_g, out_norm_b, y2h);
  k_outproj<<<dim3(3, 128), 256, 0, stream>>>(y2h, out_proj_w, out);
}

// Round 15
// 186.838 us; speedup vs baseline: 1.1220x; 1.1220x over previous
//
#include <hip/hip_runtime.h>
#include <math.h>

#define DI 384   // d_inner

typedef __attribute__((ext_vector_type(8))) short bf8v;   // 8 bf16
typedef __attribute__((ext_vector_type(4))) float f4v;    // 4 fp32

__device__ __forceinline__ f4v mfma16(bf8v a, bf8v b, f4v c) {
  return __builtin_amdgcn_mfma_f32_16x16x32_bf16(a, b, c, 0, 0, 0);
}

__device__ __forceinline__ int trf(int l) { return ((l & 63) << 6) | (l >> 6); }
__device__ __forceinline__ float gelu_f(float x) {
  return 0.5f * x * (1.0f + erff(x * 0.7071067811865475f));
}
__device__ __forceinline__ float softplus_f(float x) {
  return (x > 20.0f) ? x : log1pf(expf(x));
}
__device__ __forceinline__ unsigned short f2bf(float f) {
  unsigned u = __float_as_uint(f);
  unsigned r = (u + 0x7fff + ((u >> 16) & 1)) >> 16;
  return (unsigned short)r;
}
__device__ __forceinline__ float bf2f(unsigned short h) {
  return __uint_as_float(((unsigned)h) << 16);
}
__device__ __forceinline__ unsigned short el16(uint2 v, int i) {
  unsigned w = (i < 2) ? v.x : v.y;
  return (unsigned short)((i & 1) ? (w >> 16) : (w & 0xffffu));
}
__device__ __forceinline__ unsigned short el8(uint4 v, int i) {
  unsigned w = ((const unsigned*)&v)[i >> 1];
  return (unsigned short)((i & 1) ? (w >> 16) : (w & 0xffffu));
}
// fp32[8] -> bf16 hi/lo 8-vectors (used during GEMM staging; no separate cvt pass)
__device__ __forceinline__ void cvt8v(const float* __restrict__ p, bf8v& hv, bf8v& lv) {
#pragma unroll
  for (int i = 0; i < 8; ++i) {
    float v = p[i];
    unsigned short h = f2bf(v);
    hv[i] = (short)h;
    lv[i] = (short)f2bf(v - bf2f(h));
  }
}
// element offset in a [R][64] u16 plane, XOR-swizzled per 8-elem block
__device__ __forceinline__ int swz(int row, int col) {
  return (row << 6) + ((((col >> 3) ^ (row & 7)) << 3) | (col & 7));
}
__device__ __forceinline__ int foff(int row, int cb) {
  return (row << 6) + ((cb ^ (row & 7)) << 3);
}

// ---- in_proj (MFMA): x[8192,192] @ w[768,192]^T ; fp32 operands split at stage
__global__ __launch_bounds__(256) void k_inproj(const float* __restrict__ x,
                                                const float* __restrict__ wip,
                                                unsigned short* __restrict__ xr_hi,
                                                unsigned short* __restrict__ xr_lo,
                                                float* __restrict__ zg) {
  const int K = 192;
  __shared__ unsigned short Ah[4096], Al[4096], Bh[4096], Bl[4096];
  int tid = threadIdx.x;
  int lane = tid & 63, w = tid >> 6;
  int cl = lane & 15, kb = lane >> 4;
  int wm = w >> 1, wn = w & 1;
  int m0 = blockIdx.y * 64, n0 = blockIdx.x * 64;
  f4v acc[2][2];
  acc[0][0] = acc[0][1] = acc[1][0] = acc[1][1] = (f4v){0.f, 0.f, 0.f, 0.f};
  for (int k0 = 0; k0 < K; k0 += 64) {
#pragma unroll
    for (int u = 0; u < 2; ++u) {
      int unit = tid + u * 256;
      int row = unit >> 3, blk = unit & 7;
      int e = foff(row, blk);
      bf8v hv, lv;
      cvt8v(x + (size_t)(m0 + row) * K + k0 + blk * 8, hv, lv);
      *(bf8v*)(Ah + e) = hv;
      *(bf8v*)(Al + e) = lv;
      cvt8v(wip + (size_t)(n0 + row) * K + k0 + blk * 8, hv, lv);
      *(bf8v*)(Bh + e) = hv;
      *(bf8v*)(Bl + e) = lv;
    }
    __syncthreads();
#pragma unroll
    for (int chunk = 0; chunk < 2; ++chunk) {
      int cb = chunk * 4 + kb;
      bf8v ah[2], al[2], bh[2], bl[2];
#pragma unroll
      for (int mi = 0; mi < 2; ++mi) {
        ah[mi] = *(const bf8v*)(Ah + foff(wm * 32 + mi * 16 + cl, cb));
        al[mi] = *(const bf8v*)(Al + foff(wm * 32 + mi * 16 + cl, cb));
      }
#pragma unroll
      for (int ni = 0; ni < 2; ++ni) {
        bh[ni] = *(const bf8v*)(Bh + foff(wn * 32 + ni * 16 + cl, cb));
        bl[ni] = *(const bf8v*)(Bl + foff(wn * 32 + ni * 16 + cl, cb));
      }
#pragma unroll
      for (int mi = 0; mi < 2; ++mi)
#pragma unroll
        for (int ni = 0; ni < 2; ++ni) {
          acc[mi][ni] = mfma16(ah[mi], bh[ni], acc[mi][ni]);
          acc[mi][ni] = mfma16(ah[mi], bl[ni], acc[mi][ni]);
          acc[mi][ni] = mfma16(al[mi], bh[ni], acc[mi][ni]);
        }
    }
    __syncthreads();
  }
#pragma unroll
  for (int mi = 0; mi < 2; ++mi)
#pragma unroll
    for (int ni = 0; ni < 2; ++ni)
#pragma unroll
      for (int i = 0; i < 4; ++i) {
        int m = m0 + wm * 32 + mi * 16 + kb * 4 + i;
        int n = n0 + wn * 32 + ni * 16 + cl;
        float v = acc[mi][ni][i];
        if (n < DI) {
          unsigned short hh = f2bf(v);
          xr_hi[(size_t)m * DI + n] = hh;
          xr_lo[(size_t)m * DI + n] = f2bf(v - bf2f(hh));
        } else {
          zg[(size_t)m * DI + (n - DI)] = gelu_f(v);
        }
      }
}

// ---- depthwise 3x3 conv + bias + gelu; 8-channel vectorized, filters in LDS
__global__ __launch_bounds__(256) void k_conv(const unsigned short* __restrict__ xrh,
                                              const unsigned short* __restrict__ xrl,
                                              const float* __restrict__ cw,
                                              const float* __restrict__ cb,
                                              unsigned short* __restrict__ xhi,
                                              unsigned short* __restrict__ xlo,
                                              unsigned short* __restrict__ xthi,
                                              unsigned short* __restrict__ xtlo) {
  __shared__ float cws[3840];  // [c][jj] padded stride 10 -> 2-way bank alias (free)
  __shared__ float cbs[384];
  int tid = threadIdx.x;
  for (int t = tid; t < 3456; t += 256) {
    int cc = t / 9, jj = t % 9;
    cws[cc * 10 + jj] = cw[t];
  }
  for (int t = tid; t < 384; t += 256) cbs[t] = cb[t];
  __syncthreads();
  int idx = blockIdx.x * 256 + tid;  // over 2*4096*48
  int c8 = idx % 48;
  int c = c8 * 8;
  int lf = idx / 48;
  int b = lf >> 12;
  int l = lf & 4095;
  int h = l >> 6, w = l & 63;
  float acc[8];
#pragma unroll
  for (int i = 0; i < 8; ++i) acc[i] = cbs[c + i];
#pragma unroll
  for (int dh = -1; dh <= 1; ++dh) {
    int hh = h + dh;
    if ((unsigned)hh >= 64u) continue;
#pragma unroll
    for (int dw = -1; dw <= 1; ++dw) {
      int ww = w + dw;
      if ((unsigned)ww >= 64u) continue;
      size_t o = ((size_t)((b << 12) | (hh << 6) | ww)) * DI + c;
      uint4 hv = *(const uint4*)(xrh + o);
      uint4 lv = *(const uint4*)(xrl + o);
      int jj = (dh + 1) * 3 + (dw + 1);
#pragma unroll
      for (int i = 0; i < 8; ++i)
        acc[i] += (bf2f(el8(hv, i)) + bf2f(el8(lv, i))) * cws[(c + i) * 10 + jj];
    }
  }
  unsigned ho[4], lo4[4];
#pragma unroll
  for (int ii = 0; ii < 4; ++ii) {
    float g0 = gelu_f(acc[2 * ii]);
    float g1 = gelu_f(acc[2 * ii + 1]);
    unsigned short h0 = f2bf(g0), h1 = f2bf(g1);
    unsigned short L0 = f2bf(g0 - bf2f(h0)), L1 = f2bf(g1 - bf2f(h1));
    ho[ii] = (unsigned)h0 | ((unsigned)h1 << 16);
    lo4[ii] = (unsigned)L0 | ((unsigned)L1 << 16);
  }
  size_t oo = (size_t)lf * DI + c;
  *(uint4*)(xhi + oo) = *(const uint4*)ho;
  *(uint4*)(xlo + oo) = *(const uint4*)lo4;
  size_t tof = ((size_t)((b << 12) | trf(l))) * DI + c;  // row-contiguous in c
  *(uint4*)(xthi + tof) = *(const uint4*)ho;
  *(uint4*)(xtlo + tof) = *(const uint4*)lo4;
}

// ---- x_proj (MFMA, direction-PAIRED): one A-tile serves dir z (rows m) and
//      dir z+2 (rows 4095-m). z=0: xi->dirs{0,2}, z=1: xit->dirs{1,3}.
__global__ __launch_bounds__(256) void k_xproj(const unsigned short* __restrict__ xhi,
                                               const unsigned short* __restrict__ xlo,
                                               const unsigned short* __restrict__ xthi,
                                               const unsigned short* __restrict__ xtlo,
                                               const float* __restrict__ wxp,
                                               const float* __restrict__ dt_bias,
                                               float* __restrict__ dt_buf,
                                               unsigned short* __restrict__ Bhi,
                                               unsigned short* __restrict__ Blo,
                                               unsigned short* __restrict__ Chi,
                                               unsigned short* __restrict__ Clo) {
  const int K = DI, N = 140;
  int z = blockIdx.z;  // plane/dir-pair select
  __shared__ unsigned short Ah[4096], Al[4096];
  __shared__ unsigned short B0h[4096], B0l[4096], B1h[4096], B1l[4096];
  int tid = threadIdx.x;
  int lane = tid & 63, w = tid >> 6;
  int cl = lane & 15, kb = lane >> 4;
  int wm = w >> 1, wn = w & 1;
  int m0 = blockIdx.y * 64, n0 = blockIdx.x * 64;
  const unsigned short* xph = z ? xthi : xhi;
  const unsigned short* xpl = z ? xtlo : xlo;
  const float* wk0 = wxp + (size_t)z * N * K;
  const float* wk1 = wxp + (size_t)(z + 2) * N * K;
  f4v acc[2][2][2];  // [dir][mi][ni]
#pragma unroll
  for (int d = 0; d < 2; ++d)
#pragma unroll
    for (int mi = 0; mi < 2; ++mi)
#pragma unroll
      for (int ni = 0; ni < 2; ++ni) acc[d][mi][ni] = (f4v){0.f, 0.f, 0.f, 0.f};
  for (int k0 = 0; k0 < K; k0 += 64) {
#pragma unroll
    for (int u = 0; u < 2; ++u) {
      int unit = tid + u * 256;
      int row = unit >> 3, blk = unit & 7;
      int e = foff(row, blk);
      size_t ga = (size_t)(m0 + row) * DI + k0 + blk * 8;
      *(bf8v*)(Ah + e) = *(const bf8v*)(xph + ga);
      *(bf8v*)(Al + e) = *(const bf8v*)(xpl + ga);
      int n = n0 + row;
      if (n < N) {
        bf8v hv, lv;
        cvt8v(wk0 + (size_t)n * K + k0 + blk * 8, hv, lv);
        *(bf8v*)(B0h + e) = hv;
        *(bf8v*)(B0l + e) = lv;
        cvt8v(wk1 + (size_t)n * K + k0 + blk * 8, hv, lv);
        *(bf8v*)(B1h + e) = hv;
        *(bf8v*)(B1l + e) = lv;
      } else {
        bf8v zv = {0, 0, 0, 0, 0, 0, 0, 0};
        *(bf8v*)(B0h + e) = zv;
        *(bf8v*)(B0l + e) = zv;
        *(bf8v*)(B1h + e) = zv;
        *(bf8v*)(B1l + e) = zv;
      }
    }
    __syncthreads();
#pragma unroll
    for (int chunk = 0; chunk < 2; ++chunk) {
      int cb = chunk * 4 + kb;
      bf8v ah[2], al[2];
#pragma unroll
      for (int mi = 0; mi < 2; ++mi) {
        ah[mi] = *(const bf8v*)(Ah + foff(wm * 32 + mi * 16 + cl, cb));
        al[mi] = *(const bf8v*)(Al + foff(wm * 32 + mi * 16 + cl, cb));
      }
#pragma unroll
      for (int ni = 0; ni < 2; ++ni) {
        int brow = wn * 32 + ni * 16 + cl;
        bf8v b0h = *(const bf8v*)(B0h + foff(brow, cb));
        bf8v b0l = *(const bf8v*)(B0l + foff(brow, cb));
        bf8v b1h = *(const bf8v*)(B1h + foff(brow, cb));
        bf8v b1l = *(const bf8v*)(B1l + foff(brow, cb));
#pragma unroll
        for (int mi = 0; mi < 2; ++mi) {
          acc[0][mi][ni] = mfma16(ah[mi], b0h, acc[0][mi][ni]);
          acc[0][mi][ni] = mfma16(ah[mi], b0l, acc[0][mi][ni]);
          acc[0][mi][ni] = mfma16(al[mi], b0h, acc[0][mi][ni]);
          acc[1][mi][ni] = mfma16(ah[mi], b1h, acc[1][mi][ni]);
          acc[1][mi][ni] = mfma16(ah[mi], b1l, acc[1][mi][ni]);
          acc[1][mi][ni] = mfma16(al[mi], b1h, acc[1][mi][ni]);
        }
      }
    }
    __syncthreads();
  }
#pragma unroll
  for (int d = 0; d < 2; ++d) {
    int kd = z + d * 2;
#pragma unroll
    for (int mi = 0; mi < 2; ++mi)
#pragma unroll
      for (int ni = 0; ni < 2; ++ni)
#pragma unroll
        for (int i = 0; i < 4; ++i) {
          int m = m0 + wm * 32 + mi * 16 + kb * 4 + i;
          int n = n0 + wn * 32 + ni * 16 + cl;
          if (n >= N) continue;
          float v = acc[d][mi][ni][i];
          int b = m >> 12;
          int l = m & 4095;
          if (d) l = 4095 - l;
          if (n < 12) {
            dt_buf[(((size_t)(b * 48 + kd * 12 + n)) << 12) + l] =
                softplus_f(v + dt_bias[kd * 12 + n]);
          } else if (n < 76) {
            size_t off = (((size_t)((b * 4 + kd) << 12)) + l) * 64 + (n - 12);
            unsigned short hh = f2bf(v);
            Bhi[off] = hh;
            Blo[off] = f2bf(v - bf2f(hh));
          } else {
            size_t off = (((size_t)((b * 4 + kd) << 12)) + l) * 64 + (n - 76);
            unsigned short hh = f2bf(v);
            Chi[off] = hh;
            Clo[off] = f2bf(v - bf2f(hh));
          }
        }
  }
}

// ---- dt cumsum precompute: acum (inclusive, fp32) + chunk decay
__global__ __launch_bounds__(256) void k_dtacum(const float* __restrict__ dt_buf,
                                                const float* __restrict__ A_logs,
                                                float* __restrict__ ac_buf,
                                                float* __restrict__ cdec) {
  int bh = blockIdx.y;                           // 0..95
  int c = blockIdx.x * 4 + (threadIdx.x >> 6);   // 0..63
  int lane = threadIdx.x & 63;
  int h = bh % 48;
  size_t o = ((size_t)bh << 12) + c * 64 + lane;
  float dtv = dt_buf[o];
  float v = dtv * (-__expf(A_logs[h]));
#pragma unroll
  for (int off = 1; off < 64; off <<= 1) {
    float u = __shfl_up(v, off, 64);
    if (lane >= off) v += u;
  }
  ac_buf[o] = v;
  if (lane == 63) cdec[bh * 64 + c] = __expf(v);
}

// ---- D1 (MFMA, hi-only): single barrier per head via double-buffered xw
__global__ __launch_bounds__(256) void k_states(const unsigned short* __restrict__ xhi,
                                                const unsigned short* __restrict__ xthi,
                                                const float* __restrict__ dt_buf,
                                                const float* __restrict__ ac_buf,
                                                const unsigned short* __restrict__ Bhi,
                                                unsigned short* __restrict__ Shi) {
  int c = blockIdx.x, k = blockIdx.y >> 1, g = blockIdx.y & 1, b = blockIdx.z;
  __shared__ unsigned short Bt_h[4096];     // [n][q] transposed, swizzled
  __shared__ unsigned short xwb[2][2048];   // [p][q] swizzled, double-buffered
  int tid = threadIdx.x;
  int lane = tid & 63, w = tid >> 6;
  int cl = lane & 15, kb = lane >> 4;
  const unsigned short* xp = (k & 1) ? xthi : xhi;
  int pg = tid & 7, qq = tid >> 3;  // p=pg*4..+3, q0=qq*2
  int h0_ = k * 12 + g * 6;
  // prefetch head 0 x + dt + ac
  uint2 xgA[2], xgB[2];
#pragma unroll
  for (int qp = 0; qp < 2; ++qp) {
    int i = c * 64 + qq * 2 + qp;
    if (k & 2) i = 4095 - i;
    xgA[qp] = *(const uint2*)(xp + ((size_t)((b << 12) + i)) * DI + (g * 6) * 32 + pg * 4);
  }
  size_t dto0 = (((size_t)(b * 48 + h0_)) << 12) + c * 64 + lane;
  float dtA = dt_buf[dto0];
  float acA = ac_buf[dto0];
  float dtB, acB;
  // transpose-stage B -> Bt[n][q] (covered by first loop barrier)
  size_t Bbase = (((size_t)((b * 4 + k) << 12)) + c * 64) * 64;
  {
    int n = lane;
#pragma unroll
    for (int it = 0; it < 8; ++it) {
      int q0 = 2 * (w + it * 4);
      unsigned short h0 = Bhi[Bbase + (size_t)q0 * 64 + n];
      unsigned short h1 = Bhi[Bbase + (size_t)(q0 + 1) * 64 + n];
      *(unsigned int*)(Bt_h + swz(n, q0)) = (unsigned)h0 | ((unsigned)h1 << 16);
    }
  }
  for (int rr = 0; rr < 6; ++rr) {
    int r = g * 6 + rr;
    int h = k * 12 + r;
    float v = acA;
    float alast = __shfl(v, 63, 64);
    float wq = dtA * __expf(alast - v);
    float w0 = __shfl(wq, qq * 2, 64), w1 = __shfl(wq, qq * 2 + 1, 64);
    unsigned short* xw_h = xwb[rr & 1];
#pragma unroll
    for (int pi = 0; pi < 4; ++pi) {
      int p = pg * 4 + pi;
      unsigned short h0 = f2bf(bf2f(el16(xgA[0], pi)) * w0);
      unsigned short h1 = f2bf(bf2f(el16(xgA[1], pi)) * w1);
      *(unsigned int*)(xw_h + swz(p, qq * 2)) = (unsigned)h0 | ((unsigned)h1 << 16);
    }
    __syncthreads();  // xw[rr&1]+Bt ready; prev head's MFMA (other buffer) may lag safely
    // prefetch next head
    if (rr < 5) {
#pragma unroll
      for (int qp = 0; qp < 2; ++qp) {
        int i = c * 64 + qq * 2 + qp;
        if (k & 2) i = 4095 - i;
        xgB[qp] = *(const uint2*)(xp + ((size_t)((b << 12) + i)) * DI + (r + 1) * 32 + pg * 4);
      }
      size_t dton = (((size_t)(b * 48 + h + 1)) << 12) + c * 64 + lane;
      dtB = dt_buf[dton];
      acB = ac_buf[dton];
    }
    f4v acc0 = {0.f, 0.f, 0.f, 0.f}, acc1 = {0.f, 0.f, 0.f, 0.f};
#pragma unroll
    for (int chunk = 0; chunk < 2; ++chunk) {
      int cb_ = chunk * 4 + kb;
      bf8v bh = *(const bf8v*)(Bt_h + foff(w * 16 + cl, cb_));
      bf8v a0h = *(const bf8v*)(xw_h + foff(cl, cb_));
      bf8v a1h = *(const bf8v*)(xw_h + foff(16 + cl, cb_));
      acc0 = mfma16(a0h, bh, acc0);
      acc1 = mfma16(a1h, bh, acc1);
    }
    size_t sbase = ((size_t)(b * 48 + h) * 64 + c) * 2048;
#pragma unroll
    for (int i = 0; i < 4; ++i) {
      int prow = kb * 4 + i;
      int n = w * 16 + cl;
      Shi[sbase + (size_t)prow * 64 + n] = f2bf(acc0[i]);
      Shi[sbase + (size_t)(16 + prow) * 64 + n] = f2bf(acc1[i]);
    }
    xgA[0] = xgB[0];
    xgA[1] = xgB[1];
    dtA = dtB;
    acA = acB;
  }
}

// ---- D2: inter-chunk scan, in place bf16, 8-deep prefetched load pipeline
__global__ __launch_bounds__(256) void k_scan(unsigned short* __restrict__ Shi,
                                              const float* __restrict__ cdec) {
  int j = blockIdx.x;   // 0..7
  int bh = blockIdx.y;  // 0..95
  int tid = threadIdx.x;
  size_t base0 = (size_t)bh * 64 * 2048 + j * 256 + tid;
  float pre[8];
#pragma unroll
  for (int jj = 0; jj < 8; ++jj) pre[jj] = bf2f(Shi[base0 + (size_t)jj * 2048]);
  float S = 0.0f;
#pragma unroll 8
  for (int c = 0; c < 64; ++c) {
    float cd = cdec[bh * 64 + c];
    size_t idx = base0 + (size_t)c * 2048;
    float tmp = pre[c & 7];
    if (c + 8 < 64) pre[c & 7] = bf2f(Shi[idx + 8 * 2048]);
    Shi[idx] = f2bf(S);
    S = cd * S + tmp;
  }
}

// ---- D3 (MFMA): CB^T once (regs); per head (SINGLE barrier, double-buffered G/X):
//      Y = G_h @ x + exp(Ac)*(C @ prev^T) + D*x ; ys fp32
__global__ __launch_bounds__(256) void k_out(const unsigned short* __restrict__ xhi,
                                             const unsigned short* __restrict__ xlo,
                                             const unsigned short* __restrict__ xthi,
                                             const unsigned short* __restrict__ xtlo,
                                             const float* __restrict__ dt_buf,
                                             const float* __restrict__ ac_buf,
                                             const unsigned short* __restrict__ Bhi,
                                             const unsigned short* __restrict__ Blo,
                                             const unsigned short* __restrict__ Chi,
                                             const unsigned short* __restrict__ Clo,
                                             const float* __restrict__ Ds,
                                             const unsigned short* __restrict__ Phi,
                                             float* __restrict__ ys) {
  int c = blockIdx.x, k = blockIdx.y >> 1, g = blockIdx.y & 1, b = blockIdx.z;
  __shared__ unsigned short C_h[4096], C_l[4096];  // [q][n] swizzled
  __shared__ unsigned short Gb[2][4096];           // B hi/lo in CB phase, then G dbuf
  __shared__ unsigned short Xb[2][4096];           // X_h|X_l double-buffered
  int tid = threadIdx.x;
  int lane = tid & 63, w = tid >> 6;
  int cl = lane & 15, kb = lane >> 4;
  const unsigned short* xph = (k & 1) ? xthi : xhi;
  const unsigned short* xpl = (k & 1) ? xtlo : xlo;
  int pg = tid & 7, sq = tid >> 3;  // p=pg*4..+3, s0=sq*2
  int h0_ = k * 12 + g * 6;
  // prefetch head 0: X (wide), P frags, dt, acum
  uint2 xghA[2], xglA[2], xghB[2], xglB[2];
#pragma unroll
  for (int sp = 0; sp < 2; ++sp) {
    int i = c * 64 + sq * 2 + sp;
    if (k & 2) i = 4095 - i;
    size_t o = ((size_t)((b << 12) + i)) * DI + (g * 6) * 32 + pg * 4;
    xghA[sp] = *(const uint2*)(xph + o);
    xglA[sp] = *(const uint2*)(xpl + o);
  }
  bf8v pfA[2][2], pfB[2][2];
  {
    size_t pb = ((size_t)(b * 48 + h0_) * 64 + c) * 2048;
#pragma unroll
    for (int chunk = 0; chunk < 2; ++chunk) {
      int cb_ = chunk * 4 + kb;
      pfA[chunk][0] = *(const bf8v*)(Phi + pb + (size_t)cl * 64 + cb_ * 8);
      pfA[chunk][1] = *(const bf8v*)(Phi + pb + (size_t)(16 + cl) * 64 + cb_ * 8);
    }
  }
  size_t dto0 = (((size_t)(b * 48 + h0_)) << 12) + c * 64 + lane;
  float dtA = dt_buf[dto0];
  float vA = ac_buf[dto0];
  float dtB, vB;
  // stage C (C_h/C_l) + B (hi->Gb[0], lo->Gb[1]) for CB^T
  size_t base64 = (((size_t)((b * 4 + k) << 12)) + c * 64) * 64;
  {
    int n0 = (tid & 31) * 2;
    int qq = tid >> 5;
#pragma unroll
    for (int it = 0; it < 8; ++it) {
      int q = qq + it * 8;
      size_t off = base64 + (size_t)q * 64 + n0;
      int e = swz(q, n0);
      *(unsigned int*)(C_h + e) = *(const unsigned int*)(Chi + off);
      *(unsigned int*)(C_l + e) = *(const unsigned int*)(Clo + off);
      *(unsigned int*)(Gb[0] + e) = *(const unsigned int*)(Bhi + off);
      *(unsigned int*)(Gb[1] + e) = *(const unsigned int*)(Blo + off);
    }
  }
  __syncthreads();
  bf8v caf_h[2], caf_l[2];
#pragma unroll
  for (int chunk = 0; chunk < 2; ++chunk) {
    caf_h[chunk] = *(const bf8v*)(C_h + foff(w * 16 + cl, chunk * 4 + kb));
    caf_l[chunk] = *(const bf8v*)(C_l + foff(w * 16 + cl, chunk * 4 + kb));
  }
  f4v cbt[4];
#pragma unroll
  for (int St = 0; St < 4; ++St) cbt[St] = (f4v){0.f, 0.f, 0.f, 0.f};
#pragma unroll
  for (int St = 0; St < 4; ++St) {
    int srow = St * 16 + cl;
#pragma unroll
    for (int chunk = 0; chunk < 2; ++chunk) {
      bf8v bh = *(const bf8v*)(Gb[0] + foff(srow, chunk * 4 + kb));
      bf8v bl = *(const bf8v*)(Gb[1] + foff(srow, chunk * 4 + kb));
      cbt[St] = mfma16(caf_h[chunk], bh, cbt[St]);
      cbt[St] = mfma16(caf_h[chunk], bl, cbt[St]);
      cbt[St] = mfma16(caf_l[chunk], bh, cbt[St]);
    }
  }
  __syncthreads();  // all waves done reading B from Gb before head-0 overwrites
  for (int rr = 0; rr < 6; ++rr) {
    int r = g * 6 + rr;
    int h = k * 12 + r;
    float dtv = dtA;
    float v = vA;
    float ea = __expf(v);
    unsigned short* Gc = Gb[rr & 1];
    unsigned short* X_h = Xb[rr & 1];
    unsigned short* X_l = Xb[rr & 1] + 2048;
    // write prefetched X regs -> LDS (buffer rr&1; prev head's MFMA uses other buffer)
#pragma unroll
    for (int pi = 0; pi < 4; ++pi) {
      int p = pg * 4 + pi;
      int e = swz(p, sq * 2);
      *(unsigned int*)(X_h + e) =
          (unsigned)el16(xghA[0], pi) | ((unsigned)el16(xghA[1], pi) << 16);
      *(unsigned int*)(X_l + e) =
          (unsigned)el16(xglA[0], pi) | ((unsigned)el16(xglA[1], pi) << 16);
    }
    // build G[q][s] (hi only) from register CB; evq reused as epilogue exp(Ac[q])
    float vq[4], evq[4];
#pragma unroll
    for (int i = 0; i < 4; ++i) {
      vq[i] = __shfl(v, w * 16 + kb * 4 + i, 64);
      evq[i] = __shfl(ea, w * 16 + kb * 4 + i, 64);
    }
#pragma unroll
    for (int St = 0; St < 4; ++St) {
      int s = St * 16 + cl;
      float vs = __shfl(v, s, 64);
      float dts = __shfl(dtv, s, 64);
#pragma unroll
      for (int i = 0; i < 4; ++i) {
        int q = w * 16 + kb * 4 + i;
        float gv = (q >= s) ? cbt[St][i] * __expf(vq[i] - vs) * dts : 0.0f;
        Gc[swz(q, s)] = f2bf(gv);
      }
    }
    __syncthreads();  // single barrier: staging + G of THIS head ready
    // prefetch NEXT head's X + P + dt + acum (consumed next iteration)
    if (rr < 5) {
#pragma unroll
      for (int sp = 0; sp < 2; ++sp) {
        int i = c * 64 + sq * 2 + sp;
        if (k & 2) i = 4095 - i;
        size_t o = ((size_t)((b << 12) + i)) * DI + (r + 1) * 32 + pg * 4;
        xghB[sp] = *(const uint2*)(xph + o);
        xglB[sp] = *(const uint2*)(xpl + o);
      }
      size_t pbn = ((size_t)(b * 48 + h + 1) * 64 + c) * 2048;
#pragma unroll
      for (int chunk = 0; chunk < 2; ++chunk) {
        int cb_ = chunk * 4 + kb;
        pfB[chunk][0] = *(const bf8v*)(Phi + pbn + (size_t)cl * 64 + cb_ * 8);
        pfB[chunk][1] = *(const bf8v*)(Phi + pbn + (size_t)(16 + cl) * 64 + cb_ * 8);
      }
      size_t dton = (((size_t)(b * 48 + h + 1)) << 12) + c * 64 + lane;
      dtB = dt_buf[dton];
      vB = ac_buf[dton];
    }
    f4v aD0 = {0.f, 0.f, 0.f, 0.f}, aD1 = aD0, aO0 = aD0, aO1 = aD0;
#pragma unroll
    for (int chunk = 0; chunk < 2; ++chunk) {
      int cb_ = chunk * 4 + kb;
      int qrow = w * 16 + cl;
      bf8v gh = *(const bf8v*)(Gc + foff(qrow, cb_));
      bf8v x0h = *(const bf8v*)(X_h + foff(cl, cb_));
      bf8v x0l = *(const bf8v*)(X_l + foff(cl, cb_));
      bf8v x1h = *(const bf8v*)(X_h + foff(16 + cl, cb_));
      bf8v x1l = *(const bf8v*)(X_l + foff(16 + cl, cb_));
      aD0 = mfma16(gh, x0h, aD0);
      aD0 = mfma16(gh, x0l, aD0);
      aD1 = mfma16(gh, x1h, aD1);
      aD1 = mfma16(gh, x1l, aD1);
      aO0 = mfma16(caf_h[chunk], pfA[chunk][0], aO0);
      aO0 = mfma16(caf_l[chunk], pfA[chunk][0], aO0);
      aO1 = mfma16(caf_h[chunk], pfA[chunk][1], aO1);
      aO1 = mfma16(caf_l[chunk], pfA[chunk][1], aO1);
    }
    float D0 = Ds[h * 32 + cl], D1 = Ds[h * 32 + 16 + cl];
    size_t ybase = ((size_t)((b * 4 + k) << 12) + c * 64) * DI + r * 32;
#pragma unroll
    for (int i = 0; i < 4; ++i) {
      int q = w * 16 + kb * 4 + i;
      float eaq = evq[i];
      int e0 = swz(cl, q), e1 = swz(16 + cl, q);
      float xv0 = bf2f(X_h[e0]) + bf2f(X_l[e0]);
      float xv1 = bf2f(X_h[e1]) + bf2f(X_l[e1]);
      ys[ybase + (size_t)q * DI + cl] = aD0[i] + eaq * aO0[i] + D0 * xv0;
      ys[ybase + (size_t)q * DI + 16 + cl] = aD1[i] + eaq * aO1[i] + D1 * xv1;
    }
#pragma unroll
    for (int chunk = 0; chunk < 2; ++chunk) {
      pfA[chunk][0] = pfB[chunk][0];
      pfA[chunk][1] = pfB[chunk][1];
    }
    xghA[0] = xghB[0]; xghA[1] = xghB[1];
    xglA[0] = xglB[0]; xglA[1] = xglB[1];
    dtA = dtB;
    vA = vB;
  }
}

// ---- combine 4 directions + LayerNorm + gate -> y2 (bf16 hi only)
__global__ __launch_bounds__(128) void k_ln(const float* __restrict__ ys,
                                            const float* __restrict__ zg,
                                            const float* __restrict__ gg,
                                            const float* __restrict__ bb,
                                            unsigned short* __restrict__ y2h) {
  int row = blockIdx.x;
  int b = row >> 12, l = row & 4095;
  int l1 = trf(l);
  int l2 = 4095 - l;
  int l3 = 4095 - l1;
  int tid = threadIdx.x;
  float v[3];
  size_t base = ((size_t)(b * 4)) << 12;
#pragma unroll
  for (int j = 0; j < 3; ++j) {
    int d = tid + j * 128;
    v[j] = ys[(base + l) * DI + d] + ys[(base + 4096 + l1) * DI + d] +
           ys[(base + 8192 + l2) * DI + d] + ys[(base + 12288 + l3) * DI + d];
  }
  __shared__ float red[2];
  float s = v[0] + v[1] + v[2];
#pragma unroll
  for (int off = 32; off > 0; off >>= 1) s += __shfl_down(s, off, 64);
  if ((tid & 63) == 0) red[tid >> 6] = s;
  __syncthreads();
  float mu = (red[0] + red[1]) * (1.0f / 384.0f);
  __syncthreads();
  float d2 = 0.0f;
#pragma unroll
  for (int j = 0; j < 3; ++j) {
    float dd = v[j] - mu;
    d2 += dd * dd;
  }
#pragma unroll
  for (int off = 32; off > 0; off >>= 1) d2 += __shfl_down(d2, off, 64);
  if ((tid & 63) == 0) red[tid >> 6] = d2;
  __syncthreads();
  float rstd = rsqrtf((red[0] + red[1]) * (1.0f / 384.0f) + 1e-5f);
#pragma unroll
  for (int j = 0; j < 3; ++j) {
    int d = tid + j * 128;
    float yv = (v[j] - mu) * rstd * gg[d] + bb[d];
    float o = yv * zg[(size_t)row * DI + d];
    y2h[(size_t)row * DI + d] = f2bf(o);
  }
}

// ---- out_proj (MFMA): y2(bf16)[8192,384] @ w[192,384]^T -> out fp32 [8192,192]
__global__ __launch_bounds__(256) void k_outproj(const unsigned short* __restrict__ Ahi,
                                                 const float* __restrict__ wop,
                                                 float* __restrict__ out) {
  const int K = DI, NO = 192;
  __shared__ unsigned short Ah[4096], Bh[4096], Bl[4096];
  int tid = threadIdx.x;
  int lane = tid & 63, w = tid >> 6;
  int cl = lane & 15, kb = lane >> 4;
  int wm = w >> 1, wn = w & 1;
  int m0 = blockIdx.y * 64, n0 = blockIdx.x * 64;
  f4v acc[2][2];
  acc[0][0] = acc[0][1] = acc[1][0] = acc[1][1] = (f4v){0.f, 0.f, 0.f, 0.f};
  for (int k0 = 0; k0 < K; k0 += 64) {
#pragma unroll
    for (int u = 0; u < 2; ++u) {
      int unit = tid + u * 256;
      int row = unit >> 3, blk = unit & 7;
      int e = foff(row, blk);
      *(bf8v*)(Ah + e) = *(const bf8v*)(Ahi + (size_t)(m0 + row) * K + k0 + blk * 8);
      bf8v hv, lv;
      cvt8v(wop + (size_t)(n0 + row) * K + k0 + blk * 8, hv, lv);
      *(bf8v*)(Bh + e) = hv;
      *(bf8v*)(Bl + e) = lv;
    }
    __syncthreads();
#pragma unroll
    for (int chunk = 0; chunk < 2; ++chunk) {
      int cb = chunk * 4 + kb;
      bf8v ah[2], bh[2], bl[2];
#pragma unroll
      for (int mi = 0; mi < 2; ++mi)
        ah[mi] = *(const bf8v*)(Ah + foff(wm * 32 + mi * 16 + cl, cb));
#pragma unroll
      for (int ni = 0; ni < 2; ++ni) {
        bh[ni] = *(const bf8v*)(Bh + foff(wn * 32 + ni * 16 + cl, cb));
        bl[ni] = *(const bf8v*)(Bl + foff(wn * 32 + ni * 16 + cl, cb));
      }
#pragma unroll
      for (int mi = 0; mi < 2; ++mi)
#pragma unroll
        for (int ni = 0; ni < 2; ++ni) {
          acc[mi][ni] = mfma16(ah[mi], bh[ni], acc[mi][ni]);
          acc[mi][ni] = mfma16(ah[mi], bl[ni], acc[mi][ni]);
        }
    }
    __syncthreads();
  }
#pragma unroll
  for (int mi = 0; mi < 2; ++mi)
#pragma unroll
    for (int ni = 0; ni < 2; ++ni)
#pragma unroll
      for (int i = 0; i < 4; ++i) {
        int m = m0 + wm * 32 + mi * 16 + kb * 4 + i;
        int n = n0 + wn * 32 + ni * 16 + cl;
        out[(size_t)m * NO + n] = acc[mi][ni][i];
      }
}

extern "C" void kernel_launch(void* const* d_in, const int* in_sizes, int n_in,
                              void* d_out, int out_size, void* d_ws, size_t ws_size,
                              hipStream_t stream) {
  const float* x = (const float*)d_in[0];
  const float* in_proj_w = (const float*)d_in[1];
  const float* conv_w = (const float*)d_in[2];
  const float* conv_b = (const float*)d_in[3];
  const float* x_proj_w = (const float*)d_in[4];
  const float* A_logs = (const float*)d_in[5];
  const float* Ds = (const float*)d_in[6];
  const float* dt_bias = (const float*)d_in[7];
  const float* out_norm_g = (const float*)d_in[8];
  const float* out_norm_b = (const float*)d_in[9];
  const float* out_proj_w = (const float*)d_in[10];
  float* out = (float*)d_out;

  float* ws = (float*)d_ws;
  float* xi_raw = ws;                        // 3145728 f (xr hi/lo planes, later y2)
  float* zg = xi_raw + 3145728;              // 3145728 f
  float* dt_buf = zg + 3145728;              // 393216 f
  float* ac_buf = dt_buf + 393216;           // 393216 f
  float* cdec = ac_buf + 393216;             // 6144 f
  float* ys = cdec + 6144;                   // 12582912 f
  unsigned short* u16p = (unsigned short*)(ys + 12582912);
  unsigned short* Shi = u16p;    u16p += 12582912;   // states/prev (bf16, hi only)
  unsigned short* xi_hi = u16p;  u16p += 3145728;
  unsigned short* xi_lo = u16p;  u16p += 3145728;
  unsigned short* xit_hi = u16p; u16p += 3145728;    // transposed hi plane
  unsigned short* xit_lo = u16p; u16p += 3145728;    // transposed lo plane
  unsigned short* Bhi = u16p;    u16p += 2097152;
  unsigned short* Blo = u16p;    u16p += 2097152;
  unsigned short* Chi = u16p;    u16p += 2097152;
  unsigned short* Clo = u16p;    u16p += 2097152;
  unsigned short* xr_hi = (unsigned short*)xi_raw;  // in_proj out, dead after conv
  unsigned short* xr_lo = xr_hi + 3145728;
  unsigned short* y2h = xr_hi;                      // alias: xr dead after conv

  k_inproj<<<dim3(12, 128), 256, 0, stream>>>(x, in_proj_w, xr_hi, xr_lo, zg);
  k_conv<<<dim3(1536), 256, 0, stream>>>(xr_hi, xr_lo, conv_w, conv_b, xi_hi, xi_lo,
                                         xit_hi, xit_lo);
  k_xproj<<<dim3(3, 128, 2), 256, 0, stream>>>(xi_hi, xi_lo, xit_hi, xit_lo, x_proj_w,
                                               dt_bias, dt_buf, Bhi, Blo, Chi, Clo);
  k_dtacum<<<dim3(16, 96), 256, 0, stream>>>(dt_buf, A_logs, ac_buf, cdec);
  k_states<<<dim3(64, 8, 2), 256, 0, stream>>>(xi_hi, xit_hi, dt_buf, ac_buf, Bhi, Shi);
  k_scan<<<dim3(8, 96), 256, 0, stream>>>(Shi, cdec);
  k_out<<<dim3(64, 8, 2), 256, 0, stream>>>(xi_hi, xi_lo, xit_hi, xit_lo, dt_buf,
                                            ac_buf, Bhi, Blo, Chi, Clo, Ds, Shi, ys);
  k_ln<<<dim3(8192), 128, 0, stream>>>(ys, zg, out_norm_g, out_norm_b, y2h);
  k_outproj<<<dim3(3, 128), 256, 0, stream>>>(y2h, out_proj_w, out);
}

// Round 16
// 173.420 us; speedup vs baseline: 1.2088x; 1.0774x over previous
//
#include <hip/hip_runtime.h>
#include <math.h>

#define DI 384   // d_inner

typedef __attribute__((ext_vector_type(8))) short bf8v;   // 8 bf16
typedef __attribute__((ext_vector_type(4))) float f4v;    // 4 fp32

__device__ __forceinline__ f4v mfma16(bf8v a, bf8v b, f4v c) {
  return __builtin_amdgcn_mfma_f32_16x16x32_bf16(a, b, c, 0, 0, 0);
}

__device__ __forceinline__ int trf(int l) { return ((l & 63) << 6) | (l >> 6); }
__device__ __forceinline__ float gelu_f(float x) {
  return 0.5f * x * (1.0f + erff(x * 0.7071067811865475f));
}
__device__ __forceinline__ float softplus_f(float x) {
  return (x > 20.0f) ? x : log1pf(expf(x));
}
__device__ __forceinline__ unsigned short f2bf(float f) {
  unsigned u = __float_as_uint(f);
  unsigned r = (u + 0x7fff + ((u >> 16) & 1)) >> 16;
  return (unsigned short)r;
}
__device__ __forceinline__ float bf2f(unsigned short h) {
  return __uint_as_float(((unsigned)h) << 16);
}
__device__ __forceinline__ unsigned short el16(uint2 v, int i) {
  unsigned w = (i < 2) ? v.x : v.y;
  return (unsigned short)((i & 1) ? (w >> 16) : (w & 0xffffu));
}
__device__ __forceinline__ unsigned short el8(uint4 v, int i) {
  unsigned w = ((const unsigned*)&v)[i >> 1];
  return (unsigned short)((i & 1) ? (w >> 16) : (w & 0xffffu));
}
// fp32[8] -> bf16 hi/lo 8-vectors (used during GEMM staging; no separate cvt pass)
__device__ __forceinline__ void cvt8v(const float* __restrict__ p, bf8v& hv, bf8v& lv) {
#pragma unroll
  for (int i = 0; i < 8; ++i) {
    float v = p[i];
    unsigned short h = f2bf(v);
    hv[i] = (short)h;
    lv[i] = (short)f2bf(v - bf2f(h));
  }
}
// element offset in a [R][64] u16 plane, XOR-swizzled per 8-elem block
__device__ __forceinline__ int swz(int row, int col) {
  return (row << 6) + ((((col >> 3) ^ (row & 7)) << 3) | (col & 7));
}
__device__ __forceinline__ int foff(int row, int cb) {
  return (row << 6) + ((cb ^ (row & 7)) << 3);
}

// ---- in_proj (MFMA): x[8192,192] @ w[768,192]^T ; fp32 operands split at stage
__global__ __launch_bounds__(256) void k_inproj(const float* __restrict__ x,
                                                const float* __restrict__ wip,
                                                unsigned short* __restrict__ xr_hi,
                                                unsigned short* __restrict__ xr_lo,
                                                float* __restrict__ zg) {
  const int K = 192;
  __shared__ unsigned short Ah[4096], Al[4096], Bh[4096], Bl[4096];
  int tid = threadIdx.x;
  int lane = tid & 63, w = tid >> 6;
  int cl = lane & 15, kb = lane >> 4;
  int wm = w >> 1, wn = w & 1;
  int m0 = blockIdx.y * 64, n0 = blockIdx.x * 64;
  f4v acc[2][2];
  acc[0][0] = acc[0][1] = acc[1][0] = acc[1][1] = (f4v){0.f, 0.f, 0.f, 0.f};
  for (int k0 = 0; k0 < K; k0 += 64) {
#pragma unroll
    for (int u = 0; u < 2; ++u) {
      int unit = tid + u * 256;
      int row = unit >> 3, blk = unit & 7;
      int e = foff(row, blk);
      bf8v hv, lv;
      cvt8v(x + (size_t)(m0 + row) * K + k0 + blk * 8, hv, lv);
      *(bf8v*)(Ah + e) = hv;
      *(bf8v*)(Al + e) = lv;
      cvt8v(wip + (size_t)(n0 + row) * K + k0 + blk * 8, hv, lv);
      *(bf8v*)(Bh + e) = hv;
      *(bf8v*)(Bl + e) = lv;
    }
    __syncthreads();
#pragma unroll
    for (int chunk = 0; chunk < 2; ++chunk) {
      int cb = chunk * 4 + kb;
      bf8v ah[2], al[2], bh[2], bl[2];
#pragma unroll
      for (int mi = 0; mi < 2; ++mi) {
        ah[mi] = *(const bf8v*)(Ah + foff(wm * 32 + mi * 16 + cl, cb));
        al[mi] = *(const bf8v*)(Al + foff(wm * 32 + mi * 16 + cl, cb));
      }
#pragma unroll
      for (int ni = 0; ni < 2; ++ni) {
        bh[ni] = *(const bf8v*)(Bh + foff(wn * 32 + ni * 16 + cl, cb));
        bl[ni] = *(const bf8v*)(Bl + foff(wn * 32 + ni * 16 + cl, cb));
      }
#pragma unroll
      for (int mi = 0; mi < 2; ++mi)
#pragma unroll
        for (int ni = 0; ni < 2; ++ni) {
          acc[mi][ni] = mfma16(ah[mi], bh[ni], acc[mi][ni]);
          acc[mi][ni] = mfma16(ah[mi], bl[ni], acc[mi][ni]);
          acc[mi][ni] = mfma16(al[mi], bh[ni], acc[mi][ni]);
        }
    }
    __syncthreads();
  }
#pragma unroll
  for (int mi = 0; mi < 2; ++mi)
#pragma unroll
    for (int ni = 0; ni < 2; ++ni)
#pragma unroll
      for (int i = 0; i < 4; ++i) {
        int m = m0 + wm * 32 + mi * 16 + kb * 4 + i;
        int n = n0 + wn * 32 + ni * 16 + cl;
        float v = acc[mi][ni][i];
        if (n < DI) {
          unsigned short hh = f2bf(v);
          xr_hi[(size_t)m * DI + n] = hh;
          xr_lo[(size_t)m * DI + n] = f2bf(v - bf2f(hh));
        } else {
          zg[(size_t)m * DI + (n - DI)] = gelu_f(v);
        }
      }
}

// ---- depthwise 3x3 conv + bias + gelu; 8-wide, filters in LDS as [i][jj][c8]
//      (lane stride 1 in c8 -> conflict-free LDS reads)
__global__ __launch_bounds__(256) void k_conv(const unsigned short* __restrict__ xrh,
                                              const unsigned short* __restrict__ xrl,
                                              const float* __restrict__ cw,
                                              const float* __restrict__ cb,
                                              unsigned short* __restrict__ xhi,
                                              unsigned short* __restrict__ xlo,
                                              unsigned short* __restrict__ xthi,
                                              unsigned short* __restrict__ xtlo) {
  __shared__ float cws[3456];  // [(i*9+jj)*48 + c8]
  __shared__ float cbs[384];   // [i*48 + c8]
  int tid = threadIdx.x;
  for (int t = tid; t < 3456; t += 256) {
    int cc = t / 9, jj = t % 9;
    cws[((cc & 7) * 9 + jj) * 48 + (cc >> 3)] = cw[t];
  }
  for (int t = tid; t < 384; t += 256) cbs[(t & 7) * 48 + (t >> 3)] = cb[t];
  __syncthreads();
  int idx = blockIdx.x * 256 + tid;  // over 2*4096*48
  int c8 = idx % 48;
  int c = c8 * 8;
  int lf = idx / 48;
  int b = lf >> 12;
  int l = lf & 4095;
  int h = l >> 6, w = l & 63;
  float acc[8];
#pragma unroll
  for (int i = 0; i < 8; ++i) acc[i] = cbs[i * 48 + c8];
#pragma unroll
  for (int dh = -1; dh <= 1; ++dh) {
    int hh = h + dh;
    if ((unsigned)hh >= 64u) continue;
#pragma unroll
    for (int dw = -1; dw <= 1; ++dw) {
      int ww = w + dw;
      if ((unsigned)ww >= 64u) continue;
      size_t o = ((size_t)((b << 12) | (hh << 6) | ww)) * DI + c;
      uint4 hv = *(const uint4*)(xrh + o);
      uint4 lv = *(const uint4*)(xrl + o);
      int jj = (dh + 1) * 3 + (dw + 1);
#pragma unroll
      for (int i = 0; i < 8; ++i)
        acc[i] += (bf2f(el8(hv, i)) + bf2f(el8(lv, i))) * cws[(i * 9 + jj) * 48 + c8];
    }
  }
  unsigned ho[4], lo4[4];
#pragma unroll
  for (int ii = 0; ii < 4; ++ii) {
    float g0 = gelu_f(acc[2 * ii]);
    float g1 = gelu_f(acc[2 * ii + 1]);
    unsigned short h0 = f2bf(g0), h1 = f2bf(g1);
    unsigned short L0 = f2bf(g0 - bf2f(h0)), L1 = f2bf(g1 - bf2f(h1));
    ho[ii] = (unsigned)h0 | ((unsigned)h1 << 16);
    lo4[ii] = (unsigned)L0 | ((unsigned)L1 << 16);
  }
  size_t oo = (size_t)lf * DI + c;
  *(uint4*)(xhi + oo) = *(const uint4*)ho;
  *(uint4*)(xlo + oo) = *(const uint4*)lo4;
  size_t tof = ((size_t)((b << 12) | trf(l))) * DI + c;  // row-contiguous in c
  *(uint4*)(xthi + tof) = *(const uint4*)ho;
  *(uint4*)(xtlo + tof) = *(const uint4*)lo4;
}

// ---- x_proj (MFMA, direction-PAIRED): one A-tile serves dir z (rows m) and
//      dir z+2 (rows 4095-m). z=0: xi->dirs{0,2}, z=1: xit->dirs{1,3}.
__global__ __launch_bounds__(256) void k_xproj(const unsigned short* __restrict__ xhi,
                                               const unsigned short* __restrict__ xlo,
                                               const unsigned short* __restrict__ xthi,
                                               const unsigned short* __restrict__ xtlo,
                                               const float* __restrict__ wxp,
                                               const float* __restrict__ dt_bias,
                                               float* __restrict__ dt_buf,
                                               unsigned short* __restrict__ Bhi,
                                               unsigned short* __restrict__ Blo,
                                               unsigned short* __restrict__ Chi,
                                               unsigned short* __restrict__ Clo) {
  const int K = DI, N = 140;
  int z = blockIdx.z;  // plane/dir-pair select
  __shared__ unsigned short Ah[4096], Al[4096];
  __shared__ unsigned short B0h[4096], B0l[4096], B1h[4096], B1l[4096];
  int tid = threadIdx.x;
  int lane = tid & 63, w = tid >> 6;
  int cl = lane & 15, kb = lane >> 4;
  int wm = w >> 1, wn = w & 1;
  int m0 = blockIdx.y * 64, n0 = blockIdx.x * 64;
  const unsigned short* xph = z ? xthi : xhi;
  const unsigned short* xpl = z ? xtlo : xlo;
  const float* wk0 = wxp + (size_t)z * N * K;
  const float* wk1 = wxp + (size_t)(z + 2) * N * K;
  f4v acc[2][2][2];  // [dir][mi][ni]
#pragma unroll
  for (int d = 0; d < 2; ++d)
#pragma unroll
    for (int mi = 0; mi < 2; ++mi)
#pragma unroll
      for (int ni = 0; ni < 2; ++ni) acc[d][mi][ni] = (f4v){0.f, 0.f, 0.f, 0.f};
  for (int k0 = 0; k0 < K; k0 += 64) {
#pragma unroll
    for (int u = 0; u < 2; ++u) {
      int unit = tid + u * 256;
      int row = unit >> 3, blk = unit & 7;
      int e = foff(row, blk);
      size_t ga = (size_t)(m0 + row) * DI + k0 + blk * 8;
      *(bf8v*)(Ah + e) = *(const bf8v*)(xph + ga);
      *(bf8v*)(Al + e) = *(const bf8v*)(xpl + ga);
      int n = n0 + row;
      if (n < N) {
        bf8v hv, lv;
        cvt8v(wk0 + (size_t)n * K + k0 + blk * 8, hv, lv);
        *(bf8v*)(B0h + e) = hv;
        *(bf8v*)(B0l + e) = lv;
        cvt8v(wk1 + (size_t)n * K + k0 + blk * 8, hv, lv);
        *(bf8v*)(B1h + e) = hv;
        *(bf8v*)(B1l + e) = lv;
      } else {
        bf8v zv = {0, 0, 0, 0, 0, 0, 0, 0};
        *(bf8v*)(B0h + e) = zv;
        *(bf8v*)(B0l + e) = zv;
        *(bf8v*)(B1h + e) = zv;
        *(bf8v*)(B1l + e) = zv;
      }
    }
    __syncthreads();
#pragma unroll
    for (int chunk = 0; chunk < 2; ++chunk) {
      int cb = chunk * 4 + kb;
      bf8v ah[2], al[2];
#pragma unroll
      for (int mi = 0; mi < 2; ++mi) {
        ah[mi] = *(const bf8v*)(Ah + foff(wm * 32 + mi * 16 + cl, cb));
        al[mi] = *(const bf8v*)(Al + foff(wm * 32 + mi * 16 + cl, cb));
      }
#pragma unroll
      for (int ni = 0; ni < 2; ++ni) {
        int brow = wn * 32 + ni * 16 + cl;
        bf8v b0h = *(const bf8v*)(B0h + foff(brow, cb));
        bf8v b0l = *(const bf8v*)(B0l + foff(brow, cb));
        bf8v b1h = *(const bf8v*)(B1h + foff(brow, cb));
        bf8v b1l = *(const bf8v*)(B1l + foff(brow, cb));
#pragma unroll
        for (int mi = 0; mi < 2; ++mi) {
          acc[0][mi][ni] = mfma16(ah[mi], b0h, acc[0][mi][ni]);
          acc[0][mi][ni] = mfma16(ah[mi], b0l, acc[0][mi][ni]);
          acc[0][mi][ni] = mfma16(al[mi], b0h, acc[0][mi][ni]);
          acc[1][mi][ni] = mfma16(ah[mi], b1h, acc[1][mi][ni]);
          acc[1][mi][ni] = mfma16(ah[mi], b1l, acc[1][mi][ni]);
          acc[1][mi][ni] = mfma16(al[mi], b1h, acc[1][mi][ni]);
        }
      }
    }
    __syncthreads();
  }
#pragma unroll
  for (int d = 0; d < 2; ++d) {
    int kd = z + d * 2;
#pragma unroll
    for (int mi = 0; mi < 2; ++mi)
#pragma unroll
      for (int ni = 0; ni < 2; ++ni)
#pragma unroll
        for (int i = 0; i < 4; ++i) {
          int m = m0 + wm * 32 + mi * 16 + kb * 4 + i;
          int n = n0 + wn * 32 + ni * 16 + cl;
          if (n >= N) continue;
          float v = acc[d][mi][ni][i];
          int b = m >> 12;
          int l = m & 4095;
          if (d) l = 4095 - l;
          if (n < 12) {
            dt_buf[(((size_t)(b * 48 + kd * 12 + n)) << 12) + l] =
                softplus_f(v + dt_bias[kd * 12 + n]);
          } else if (n < 76) {
            size_t off = (((size_t)((b * 4 + kd) << 12)) + l) * 64 + (n - 12);
            unsigned short hh = f2bf(v);
            Bhi[off] = hh;
            Blo[off] = f2bf(v - bf2f(hh));
          } else {
            size_t off = (((size_t)((b * 4 + kd) << 12)) + l) * 64 + (n - 76);
            unsigned short hh = f2bf(v);
            Chi[off] = hh;
            Clo[off] = f2bf(v - bf2f(hh));
          }
        }
  }
}

// ---- dt cumsum precompute: acum (inclusive, fp32) + chunk decay
__global__ __launch_bounds__(256) void k_dtacum(const float* __restrict__ dt_buf,
                                                const float* __restrict__ A_logs,
                                                float* __restrict__ ac_buf,
                                                float* __restrict__ cdec) {
  int bh = blockIdx.y;                           // 0..95
  int c = blockIdx.x * 4 + (threadIdx.x >> 6);   // 0..63
  int lane = threadIdx.x & 63;
  int h = bh % 48;
  size_t o = ((size_t)bh << 12) + c * 64 + lane;
  float dtv = dt_buf[o];
  float v = dtv * (-__expf(A_logs[h]));
#pragma unroll
  for (int off = 1; off < 64; off <<= 1) {
    float u = __shfl_up(v, off, 64);
    if (lane >= off) v += u;
  }
  ac_buf[o] = v;
  if (lane == 63) cdec[bh * 64 + c] = __expf(v);
}

// ---- D1 (MFMA, hi-only): single barrier per head via double-buffered xw
__global__ __launch_bounds__(256) void k_states(const unsigned short* __restrict__ xhi,
                                                const unsigned short* __restrict__ xthi,
                                                const float* __restrict__ dt_buf,
                                                const float* __restrict__ ac_buf,
                                                const unsigned short* __restrict__ Bhi,
                                                unsigned short* __restrict__ Shi) {
  int c = blockIdx.x, k = blockIdx.y >> 1, g = blockIdx.y & 1, b = blockIdx.z;
  __shared__ unsigned short Bt_h[4096];     // [n][q] transposed, swizzled
  __shared__ unsigned short xwb[2][2048];   // [p][q] swizzled, double-buffered
  int tid = threadIdx.x;
  int lane = tid & 63, w = tid >> 6;
  int cl = lane & 15, kb = lane >> 4;
  const unsigned short* xp = (k & 1) ? xthi : xhi;
  int pg = tid & 7, qq = tid >> 3;  // p=pg*4..+3, q0=qq*2
  int h0_ = k * 12 + g * 6;
  // prefetch head 0 x + dt + ac
  uint2 xgA[2], xgB[2];
#pragma unroll
  for (int qp = 0; qp < 2; ++qp) {
    int i = c * 64 + qq * 2 + qp;
    if (k & 2) i = 4095 - i;
    xgA[qp] = *(const uint2*)(xp + ((size_t)((b << 12) + i)) * DI + (g * 6) * 32 + pg * 4);
  }
  size_t dto0 = (((size_t)(b * 48 + h0_)) << 12) + c * 64 + lane;
  float dtA = dt_buf[dto0];
  float acA = ac_buf[dto0];
  float dtB, acB;
  // transpose-stage B -> Bt[n][q] (covered by first loop barrier)
  size_t Bbase = (((size_t)((b * 4 + k) << 12)) + c * 64) * 64;
  {
    int n = lane;
#pragma unroll
    for (int it = 0; it < 8; ++it) {
      int q0 = 2 * (w + it * 4);
      unsigned short h0 = Bhi[Bbase + (size_t)q0 * 64 + n];
      unsigned short h1 = Bhi[Bbase + (size_t)(q0 + 1) * 64 + n];
      *(unsigned int*)(Bt_h + swz(n, q0)) = (unsigned)h0 | ((unsigned)h1 << 16);
    }
  }
  for (int rr = 0; rr < 6; ++rr) {
    int r = g * 6 + rr;
    int h = k * 12 + r;
    float v = acA;
    float alast = __shfl(v, 63, 64);
    float wq = dtA * __expf(alast - v);
    float w0 = __shfl(wq, qq * 2, 64), w1 = __shfl(wq, qq * 2 + 1, 64);
    unsigned short* xw_h = xwb[rr & 1];
#pragma unroll
    for (int pi = 0; pi < 4; ++pi) {
      int p = pg * 4 + pi;
      unsigned short h0 = f2bf(bf2f(el16(xgA[0], pi)) * w0);
      unsigned short h1 = f2bf(bf2f(el16(xgA[1], pi)) * w1);
      *(unsigned int*)(xw_h + swz(p, qq * 2)) = (unsigned)h0 | ((unsigned)h1 << 16);
    }
    __syncthreads();  // xw[rr&1]+Bt ready; prev head's MFMA (other buffer) may lag safely
    // prefetch next head
    if (rr < 5) {
#pragma unroll
      for (int qp = 0; qp < 2; ++qp) {
        int i = c * 64 + qq * 2 + qp;
        if (k & 2) i = 4095 - i;
        xgB[qp] = *(const uint2*)(xp + ((size_t)((b << 12) + i)) * DI + (r + 1) * 32 + pg * 4);
      }
      size_t dton = (((size_t)(b * 48 + h + 1)) << 12) + c * 64 + lane;
      dtB = dt_buf[dton];
      acB = ac_buf[dton];
    }
    f4v acc0 = {0.f, 0.f, 0.f, 0.f}, acc1 = {0.f, 0.f, 0.f, 0.f};
#pragma unroll
    for (int chunk = 0; chunk < 2; ++chunk) {
      int cb_ = chunk * 4 + kb;
      bf8v bh = *(const bf8v*)(Bt_h + foff(w * 16 + cl, cb_));
      bf8v a0h = *(const bf8v*)(xw_h + foff(cl, cb_));
      bf8v a1h = *(const bf8v*)(xw_h + foff(16 + cl, cb_));
      acc0 = mfma16(a0h, bh, acc0);
      acc1 = mfma16(a1h, bh, acc1);
    }
    size_t sbase = ((size_t)(b * 48 + h) * 64 + c) * 2048;
#pragma unroll
    for (int i = 0; i < 4; ++i) {
      int prow = kb * 4 + i;
      int n = w * 16 + cl;
      Shi[sbase + (size_t)prow * 64 + n] = f2bf(acc0[i]);
      Shi[sbase + (size_t)(16 + prow) * 64 + n] = f2bf(acc1[i]);
    }
    xgA[0] = xgB[0];
    xgA[1] = xgB[1];
    dtA = dtB;
    acA = acB;
  }
}

// ---- D2: inter-chunk scan, in place bf16, 8-deep prefetched load pipeline
__global__ __launch_bounds__(256) void k_scan(unsigned short* __restrict__ Shi,
                                              const float* __restrict__ cdec) {
  int j = blockIdx.x;   // 0..7
  int bh = blockIdx.y;  // 0..95
  int tid = threadIdx.x;
  size_t base0 = (size_t)bh * 64 * 2048 + j * 256 + tid;
  float pre[8];
#pragma unroll
  for (int jj = 0; jj < 8; ++jj) pre[jj] = bf2f(Shi[base0 + (size_t)jj * 2048]);
  float S = 0.0f;
#pragma unroll 8
  for (int c = 0; c < 64; ++c) {
    float cd = cdec[bh * 64 + c];
    size_t idx = base0 + (size_t)c * 2048;
    float tmp = pre[c & 7];
    if (c + 8 < 64) pre[c & 7] = bf2f(Shi[idx + 8 * 2048]);
    Shi[idx] = f2bf(S);
    S = cd * S + tmp;
  }
}

// ---- D3 (MFMA): CB^T once (regs); per head (SINGLE barrier, double-buffered G/X):
//      Y = G_h @ x + exp(Ac)*(C @ prev^T) + D*x ; ys fp32
__global__ __launch_bounds__(256) void k_out(const unsigned short* __restrict__ xhi,
                                             const unsigned short* __restrict__ xlo,
                                             const unsigned short* __restrict__ xthi,
                                             const unsigned short* __restrict__ xtlo,
                                             const float* __restrict__ dt_buf,
                                             const float* __restrict__ ac_buf,
                                             const unsigned short* __restrict__ Bhi,
                                             const unsigned short* __restrict__ Blo,
                                             const unsigned short* __restrict__ Chi,
                                             const unsigned short* __restrict__ Clo,
                                             const float* __restrict__ Ds,
                                             const unsigned short* __restrict__ Phi,
                                             float* __restrict__ ys) {
  int c = blockIdx.x, k = blockIdx.y >> 1, g = blockIdx.y & 1, b = blockIdx.z;
  __shared__ unsigned short C_h[4096], C_l[4096];  // [q][n] swizzled
  __shared__ unsigned short Gb[2][4096];           // B hi/lo in CB phase, then G dbuf
  __shared__ unsigned short Xb[2][4096];           // X_h|X_l double-buffered
  int tid = threadIdx.x;
  int lane = tid & 63, w = tid >> 6;
  int cl = lane & 15, kb = lane >> 4;
  const unsigned short* xph = (k & 1) ? xthi : xhi;
  const unsigned short* xpl = (k & 1) ? xtlo : xlo;
  int pg = tid & 7, sq = tid >> 3;  // p=pg*4..+3, s0=sq*2
  int h0_ = k * 12 + g * 6;
  // prefetch head 0: X (wide), P frags, dt, acum
  uint2 xghA[2], xglA[2], xghB[2], xglB[2];
#pragma unroll
  for (int sp = 0; sp < 2; ++sp) {
    int i = c * 64 + sq * 2 + sp;
    if (k & 2) i = 4095 - i;
    size_t o = ((size_t)((b << 12) + i)) * DI + (g * 6) * 32 + pg * 4;
    xghA[sp] = *(const uint2*)(xph + o);
    xglA[sp] = *(const uint2*)(xpl + o);
  }
  bf8v pfA[2][2], pfB[2][2];
  {
    size_t pb = ((size_t)(b * 48 + h0_) * 64 + c) * 2048;
#pragma unroll
    for (int chunk = 0; chunk < 2; ++chunk) {
      int cb_ = chunk * 4 + kb;
      pfA[chunk][0] = *(const bf8v*)(Phi + pb + (size_t)cl * 64 + cb_ * 8);
      pfA[chunk][1] = *(const bf8v*)(Phi + pb + (size_t)(16 + cl) * 64 + cb_ * 8);
    }
  }
  size_t dto0 = (((size_t)(b * 48 + h0_)) << 12) + c * 64 + lane;
  float dtA = dt_buf[dto0];
  float vA = ac_buf[dto0];
  float dtB, vB;
  // stage C (C_h/C_l) + B (hi->Gb[0], lo->Gb[1]) for CB^T
  size_t base64 = (((size_t)((b * 4 + k) << 12)) + c * 64) * 64;
  {
    int n0 = (tid & 31) * 2;
    int qq = tid >> 5;
#pragma unroll
    for (int it = 0; it < 8; ++it) {
      int q = qq + it * 8;
      size_t off = base64 + (size_t)q * 64 + n0;
      int e = swz(q, n0);
      *(unsigned int*)(C_h + e) = *(const unsigned int*)(Chi + off);
      *(unsigned int*)(C_l + e) = *(const unsigned int*)(Clo + off);
      *(unsigned int*)(Gb[0] + e) = *(const unsigned int*)(Bhi + off);
      *(unsigned int*)(Gb[1] + e) = *(const unsigned int*)(Blo + off);
    }
  }
  __syncthreads();
  bf8v caf_h[2], caf_l[2];
#pragma unroll
  for (int chunk = 0; chunk < 2; ++chunk) {
    caf_h[chunk] = *(const bf8v*)(C_h + foff(w * 16 + cl, chunk * 4 + kb));
    caf_l[chunk] = *(const bf8v*)(C_l + foff(w * 16 + cl, chunk * 4 + kb));
  }
  f4v cbt[4];
#pragma unroll
  for (int St = 0; St < 4; ++St) cbt[St] = (f4v){0.f, 0.f, 0.f, 0.f};
#pragma unroll
  for (int St = 0; St < 4; ++St) {
    int srow = St * 16 + cl;
#pragma unroll
    for (int chunk = 0; chunk < 2; ++chunk) {
      bf8v bh = *(const bf8v*)(Gb[0] + foff(srow, chunk * 4 + kb));
      bf8v bl = *(const bf8v*)(Gb[1] + foff(srow, chunk * 4 + kb));
      cbt[St] = mfma16(caf_h[chunk], bh, cbt[St]);
      cbt[St] = mfma16(caf_h[chunk], bl, cbt[St]);
      cbt[St] = mfma16(caf_l[chunk], bh, cbt[St]);
    }
  }
  __syncthreads();  // all waves done reading B from Gb before head-0 overwrites
  for (int rr = 0; rr < 6; ++rr) {
    int r = g * 6 + rr;
    int h = k * 12 + r;
    float dtv = dtA;
    float v = vA;
    float ea = __expf(v);
    unsigned short* Gc = Gb[rr & 1];
    unsigned short* X_h = Xb[rr & 1];
    unsigned short* X_l = Xb[rr & 1] + 2048;
    // write prefetched X regs -> LDS (buffer rr&1; prev head's MFMA uses other buffer)
#pragma unroll
    for (int pi = 0; pi < 4; ++pi) {
      int p = pg * 4 + pi;
      int e = swz(p, sq * 2);
      *(unsigned int*)(X_h + e) =
          (unsigned)el16(xghA[0], pi) | ((unsigned)el16(xghA[1], pi) << 16);
      *(unsigned int*)(X_l + e) =
          (unsigned)el16(xglA[0], pi) | ((unsigned)el16(xglA[1], pi) << 16);
    }
    // build G[q][s] (hi only) from register CB; evq reused as epilogue exp(Ac[q])
    float vq[4], evq[4];
#pragma unroll
    for (int i = 0; i < 4; ++i) {
      vq[i] = __shfl(v, w * 16 + kb * 4 + i, 64);
      evq[i] = __shfl(ea, w * 16 + kb * 4 + i, 64);
    }
#pragma unroll
    for (int St = 0; St < 4; ++St) {
      int s = St * 16 + cl;
      float vs = __shfl(v, s, 64);
      float dts = __shfl(dtv, s, 64);
#pragma unroll
      for (int i = 0; i < 4; ++i) {
        int q = w * 16 + kb * 4 + i;
        float gv = (q >= s) ? cbt[St][i] * __expf(vq[i] - vs) * dts : 0.0f;
        Gc[swz(q, s)] = f2bf(gv);
      }
    }
    __syncthreads();  // single barrier: staging + G of THIS head ready
    // prefetch NEXT head's X + P + dt + acum (consumed next iteration)
    if (rr < 5) {
#pragma unroll
      for (int sp = 0; sp < 2; ++sp) {
        int i = c * 64 + sq * 2 + sp;
        if (k & 2) i = 4095 - i;
        size_t o = ((size_t)((b << 12) + i)) * DI + (r + 1) * 32 + pg * 4;
        xghB[sp] = *(const uint2*)(xph + o);
        xglB[sp] = *(const uint2*)(xpl + o);
      }
      size_t pbn = ((size_t)(b * 48 + h + 1) * 64 + c) * 2048;
#pragma unroll
      for (int chunk = 0; chunk < 2; ++chunk) {
        int cb_ = chunk * 4 + kb;
        pfB[chunk][0] = *(const bf8v*)(Phi + pbn + (size_t)cl * 64 + cb_ * 8);
        pfB[chunk][1] = *(const bf8v*)(Phi + pbn + (size_t)(16 + cl) * 64 + cb_ * 8);
      }
      size_t dton = (((size_t)(b * 48 + h + 1)) << 12) + c * 64 + lane;
      dtB = dt_buf[dton];
      vB = ac_buf[dton];
    }
    f4v aD0 = {0.f, 0.f, 0.f, 0.f}, aD1 = aD0, aO0 = aD0, aO1 = aD0;
#pragma unroll
    for (int chunk = 0; chunk < 2; ++chunk) {
      int cb_ = chunk * 4 + kb;
      int qrow = w * 16 + cl;
      bf8v gh = *(const bf8v*)(Gc + foff(qrow, cb_));
      bf8v x0h = *(const bf8v*)(X_h + foff(cl, cb_));
      bf8v x0l = *(const bf8v*)(X_l + foff(cl, cb_));
      bf8v x1h = *(const bf8v*)(X_h + foff(16 + cl, cb_));
      bf8v x1l = *(const bf8v*)(X_l + foff(16 + cl, cb_));
      aD0 = mfma16(gh, x0h, aD0);
      aD0 = mfma16(gh, x0l, aD0);
      aD1 = mfma16(gh, x1h, aD1);
      aD1 = mfma16(gh, x1l, aD1);
      aO0 = mfma16(caf_h[chunk], pfA[chunk][0], aO0);
      aO0 = mfma16(caf_l[chunk], pfA[chunk][0], aO0);
      aO1 = mfma16(caf_h[chunk], pfA[chunk][1], aO1);
      aO1 = mfma16(caf_l[chunk], pfA[chunk][1], aO1);
    }
    float D0 = Ds[h * 32 + cl], D1 = Ds[h * 32 + 16 + cl];
    size_t ybase = ((size_t)((b * 4 + k) << 12) + c * 64) * DI + r * 32;
#pragma unroll
    for (int i = 0; i < 4; ++i) {
      int q = w * 16 + kb * 4 + i;
      float eaq = evq[i];
      int e0 = swz(cl, q), e1 = swz(16 + cl, q);
      float xv0 = bf2f(X_h[e0]) + bf2f(X_l[e0]);
      float xv1 = bf2f(X_h[e1]) + bf2f(X_l[e1]);
      ys[ybase + (size_t)q * DI + cl] = aD0[i] + eaq * aO0[i] + D0 * xv0;
      ys[ybase + (size_t)q * DI + 16 + cl] = aD1[i] + eaq * aO1[i] + D1 * xv1;
    }
#pragma unroll
    for (int chunk = 0; chunk < 2; ++chunk) {
      pfA[chunk][0] = pfB[chunk][0];
      pfA[chunk][1] = pfB[chunk][1];
    }
    xghA[0] = xghB[0]; xghA[1] = xghB[1];
    xglA[0] = xglB[0]; xglA[1] = xglB[1];
    dtA = dtB;
    vA = vB;
  }
}

// ---- combine 4 directions + LayerNorm + gate -> y2 (bf16 hi only)
__global__ __launch_bounds__(128) void k_ln(const float* __restrict__ ys,
                                            const float* __restrict__ zg,
                                            const float* __restrict__ gg,
                                            const float* __restrict__ bb,
                                            unsigned short* __restrict__ y2h) {
  int row = blockIdx.x;
  int b = row >> 12, l = row & 4095;
  int l1 = trf(l);
  int l2 = 4095 - l;
  int l3 = 4095 - l1;
  int tid = threadIdx.x;
  float v[3];
  size_t base = ((size_t)(b * 4)) << 12;
#pragma unroll
  for (int j = 0; j < 3; ++j) {
    int d = tid + j * 128;
    v[j] = ys[(base + l) * DI + d] + ys[(base + 4096 + l1) * DI + d] +
           ys[(base + 8192 + l2) * DI + d] + ys[(base + 12288 + l3) * DI + d];
  }
  __shared__ float red[2];
  float s = v[0] + v[1] + v[2];
#pragma unroll
  for (int off = 32; off > 0; off >>= 1) s += __shfl_down(s, off, 64);
  if ((tid & 63) == 0) red[tid >> 6] = s;
  __syncthreads();
  float mu = (red[0] + red[1]) * (1.0f / 384.0f);
  __syncthreads();
  float d2 = 0.0f;
#pragma unroll
  for (int j = 0; j < 3; ++j) {
    float dd = v[j] - mu;
    d2 += dd * dd;
  }
#pragma unroll
  for (int off = 32; off > 0; off >>= 1) d2 += __shfl_down(d2, off, 64);
  if ((tid & 63) == 0) red[tid >> 6] = d2;
  __syncthreads();
  float rstd = rsqrtf((red[0] + red[1]) * (1.0f / 384.0f) + 1e-5f);
#pragma unroll
  for (int j = 0; j < 3; ++j) {
    int d = tid + j * 128;
    float yv = (v[j] - mu) * rstd * gg[d] + bb[d];
    float o = yv * zg[(size_t)row * DI + d];
    y2h[(size_t)row * DI + d] = f2bf(o);
  }
}

// ---- out_proj (MFMA): y2(bf16)[8192,384] @ w[192,384]^T -> out fp32 [8192,192]
__global__ __launch_bounds__(256) void k_outproj(const unsigned short* __restrict__ Ahi,
                                                 const float* __restrict__ wop,
                                                 float* __restrict__ out) {
  const int K = DI, NO = 192;
  __shared__ unsigned short Ah[4096], Bh[4096], Bl[4096];
  int tid = threadIdx.x;
  int lane = tid & 63, w = tid >> 6;
  int cl = lane & 15, kb = lane >> 4;
  int wm = w >> 1, wn = w & 1;
  int m0 = blockIdx.y * 64, n0 = blockIdx.x * 64;
  f4v acc[2][2];
  acc[0][0] = acc[0][1] = acc[1][0] = acc[1][1] = (f4v){0.f, 0.f, 0.f, 0.f};
  for (int k0 = 0; k0 < K; k0 += 64) {
#pragma unroll
    for (int u = 0; u < 2; ++u) {
      int unit = tid + u * 256;
      int row = unit >> 3, blk = unit & 7;
      int e = foff(row, blk);
      *(bf8v*)(Ah + e) = *(const bf8v*)(Ahi + (size_t)(m0 + row) * K + k0 + blk * 8);
      bf8v hv, lv;
      cvt8v(wop + (size_t)(n0 + row) * K + k0 + blk * 8, hv, lv);
      *(bf8v*)(Bh + e) = hv;
      *(bf8v*)(Bl + e) = lv;
    }
    __syncthreads();
#pragma unroll
    for (int chunk = 0; chunk < 2; ++chunk) {
      int cb = chunk * 4 + kb;
      bf8v ah[2], bh[2], bl[2];
#pragma unroll
      for (int mi = 0; mi < 2; ++mi)
        ah[mi] = *(const bf8v*)(Ah + foff(wm * 32 + mi * 16 + cl, cb));
#pragma unroll
      for (int ni = 0; ni < 2; ++ni) {
        bh[ni] = *(const bf8v*)(Bh + foff(wn * 32 + ni * 16 + cl, cb));
        bl[ni] = *(const bf8v*)(Bl + foff(wn * 32 + ni * 16 + cl, cb));
      }
#pragma unroll
      for (int mi = 0; mi < 2; ++mi)
#pragma unroll
        for (int ni = 0; ni < 2; ++ni) {
          acc[mi][ni] = mfma16(ah[mi], bh[ni], acc[mi][ni]);
          acc[mi][ni] = mfma16(ah[mi], bl[ni], acc[mi][ni]);
        }
    }
    __syncthreads();
  }
#pragma unroll
  for (int mi = 0; mi < 2; ++mi)
#pragma unroll
    for (int ni = 0; ni < 2; ++ni)
#pragma unroll
      for (int i = 0; i < 4; ++i) {
        int m = m0 + wm * 32 + mi * 16 + kb * 4 + i;
        int n = n0 + wn * 32 + ni * 16 + cl;
        out[(size_t)m * NO + n] = acc[mi][ni][i];
      }
}

extern "C" void kernel_launch(void* const* d_in, const int* in_sizes, int n_in,
                              void* d_out, int out_size, void* d_ws, size_t ws_size,
                              hipStream_t stream) {
  const float* x = (const float*)d_in[0];
  const float* in_proj_w = (const float*)d_in[1];
  const float* conv_w = (const float*)d_in[2];
  const float* conv_b = (const float*)d_in[3];
  const float* x_proj_w = (const float*)d_in[4];
  const float* A_logs = (const float*)d_in[5];
  const float* Ds = (const float*)d_in[6];
  const float* dt_bias = (const float*)d_in[7];
  const float* out_norm_g = (const float*)d_in[8];
  const float* out_norm_b = (const float*)d_in[9];
  const float* out_proj_w = (const float*)d_in[10];
  float* out = (float*)d_out;

  float* ws = (float*)d_ws;
  float* xi_raw = ws;                        // 3145728 f (xr hi/lo planes, later y2)
  float* zg = xi_raw + 3145728;              // 3145728 f
  float* dt_buf = zg + 3145728;              // 393216 f
  float* ac_buf = dt_buf + 393216;           // 393216 f
  float* cdec = ac_buf + 393216;             // 6144 f
  float* ys = cdec + 6144;                   // 12582912 f
  unsigned short* u16p = (unsigned short*)(ys + 12582912);
  unsigned short* Shi = u16p;    u16p += 12582912;   // states/prev (bf16, hi only)
  unsigned short* xi_hi = u16p;  u16p += 3145728;
  unsigned short* xi_lo = u16p;  u16p += 3145728;
  unsigned short* xit_hi = u16p; u16p += 3145728;    // transposed hi plane
  unsigned short* xit_lo = u16p; u16p += 3145728;    // transposed lo plane
  unsigned short* Bhi = u16p;    u16p += 2097152;
  unsigned short* Blo = u16p;    u16p += 2097152;
  unsigned short* Chi = u16p;    u16p += 2097152;
  unsigned short* Clo = u16p;    u16p += 2097152;
  unsigned short* xr_hi = (unsigned short*)xi_raw;  // in_proj out, dead after conv
  unsigned short* xr_lo = xr_hi + 3145728;
  unsigned short* y2h = xr_hi;                      // alias: xr dead after conv

  k_inproj<<<dim3(12, 128), 256, 0, stream>>>(x, in_proj_w, xr_hi, xr_lo, zg);
  k_conv<<<dim3(1536), 256, 0, stream>>>(xr_hi, xr_lo, conv_w, conv_b, xi_hi, xi_lo,
                                         xit_hi, xit_lo);
  k_xproj<<<dim3(3, 128, 2), 256, 0, stream>>>(xi_hi, xi_lo, xit_hi, xit_lo, x_proj_w,
                                               dt_bias, dt_buf, Bhi, Blo, Chi, Clo);
  k_dtacum<<<dim3(16, 96), 256, 0, stream>>>(dt_buf, A_logs, ac_buf, cdec);
  k_states<<<dim3(64, 8, 2), 256, 0, stream>>>(xi_hi, xit_hi, dt_buf, ac_buf, Bhi, Shi);
  k_scan<<<dim3(8, 96), 256, 0, stream>>>(Shi, cdec);
  k_out<<<dim3(64, 8, 2), 256, 0, stream>>>(xi_hi, xi_lo, xit_hi, xit_lo, dt_buf,
                                            ac_buf, Bhi, Blo, Chi, Clo, Ds, Shi, ys);
  k_ln<<<dim3(8192), 128, 0, stream>>>(ys, zg, out_norm_g, out_norm_b, y2h);
  k_outproj<<<dim3(3, 128), 256, 0, stream>>>(y2h, out_proj_w, out);
}